// Round 3
// baseline (753.009 us; speedup 1.0000x reference)
//
#include <hip/hip_runtime.h>
#include <hip/hip_bf16.h>
#include <math.h>

// Problem constants
#define U_   300
#define K_   19
#define FC_  100
#define B_   256
#define L_   1000
#define P_   140     // pooled length: windows l = 7p .. 7p+6, p < 140 (l <= 979)
#define EPS_ 1e-5f
#define UB_  20      // units per block in stage 1 (5 quads of 4)

// LDS padding for xs: phys(i) = i + (i>>2)  -> lane float4-stride 5 (odd),
// so wave b128 reads tile all 32 banks.
__device__ __forceinline__ int xpad(int i) { return i + (i >> 2); }

// ---------------------------------------------------------------------------
// Stage 1: conv(4->300,K=19) + BN1 + maxpool(7,7) + exp  -> pooled (B,U,P)
// Block: 256 threads = (one batch b, 20 units as 5 quads).
// Thread c<245 owns outputs l in [4c,4c+3]; sliding window in a 4-register
// rotating buffer (static indices after full unroll). 4 units share each
// window pass -> LDS reads are ~10% of FMA cycles. Weights/BN are
// wave-uniform -> s_load, SGPR FMA operands.
// exp(max(..)) == exp of max (exp monotone) -> one __expf per pooled output.
// ---------------------------------------------------------------------------
__global__ __launch_bounds__(256, 4)
void conv_pool_k(const float4* __restrict__ x4,      // (B, L) as float4 over D=4
                 const float* __restrict__ w_conv,   // (U, 4, 19)
                 const float* __restrict__ b_conv,
                 const float* __restrict__ g1,
                 const float* __restrict__ be1,
                 const float* __restrict__ m1,
                 const float* __restrict__ v1,
                 float* __restrict__ pooled)         // (B, U, P)
{
    __shared__ float4 xs[1250];                      // padded 1000 -> 1250
    __shared__ float  ybuf[4][980];
    const int tid = threadIdx.x;
    const int b   = blockIdx.y;
    const int u0  = blockIdx.x * UB_;

    for (int i = tid; i < 1000; i += 256) xs[xpad(i)] = x4[b * 1000 + i];
    __syncthreads();

    const int c = tid;
    const float4* __restrict__ xp = &xs[5 * c];      // phys(4c) = 5c

    for (int uu = 0; uu < UB_; uu += 4) {
        const int u = u0 + uu;
        float s1[4], o1[4];
#pragma unroll
        for (int q = 0; q < 4; ++q) {
            s1[q] = g1[u + q] / sqrtf(v1[u + q] + EPS_);
            o1[q] = (b_conv[u + q] - m1[u + q]) * s1[q] + be1[u + q];
        }
        const float* __restrict__ w = w_conv + u * 76;  // 4 units x 76 floats

        if (c < 245) {
            float4 r[4];
            r[0] = xp[0]; r[1] = xp[1]; r[2] = xp[2]; r[3] = xp[3];
            float a[4][4];
#pragma unroll
            for (int q = 0; q < 4; ++q)
#pragma unroll
                for (int t = 0; t < 4; ++t) a[q][t] = 0.f;

#pragma unroll
            for (int k = 0; k < K_; ++k) {
#pragma unroll
                for (int t = 0; t < 4; ++t) {
                    const float4 xv = r[(k + t) & 3];
#pragma unroll
                    for (int q = 0; q < 4; ++q) {
                        a[q][t] = fmaf(xv.x, w[q * 76 +      k], a[q][t]);
                        a[q][t] = fmaf(xv.y, w[q * 76 + 19 + k], a[q][t]);
                        a[q][t] = fmaf(xv.z, w[q * 76 + 38 + k], a[q][t]);
                        a[q][t] = fmaf(xv.w, w[q * 76 + 57 + k], a[q][t]);
                    }
                }
                if (k < K_ - 1) {
                    const int j = k + 4;
                    r[k & 3] = xp[j + (j >> 2)];
                }
            }
#pragma unroll
            for (int q = 0; q < 4; ++q)
                *(float4*)&ybuf[q][4 * c] =
                    make_float4(fmaf(a[q][0], s1[q], o1[q]),
                                fmaf(a[q][1], s1[q], o1[q]),
                                fmaf(a[q][2], s1[q], o1[q]),
                                fmaf(a[q][3], s1[q], o1[q]));
        }
        __syncthreads();

        // pool 4 units: 560 outputs, stride-7 scalar reads (7 coprime 32)
        for (int pp = tid; pp < 4 * P_; pp += 256) {
            const int which = pp / P_;
            const int p = pp - which * P_;
            const float* yb = &ybuf[which][7 * p];
            float m = yb[0];
#pragma unroll
            for (int t = 1; t < 7; ++t) m = fmaxf(m, yb[t]);
            pooled[((size_t)b * U_ + (u + which)) * P_ + p] = __expf(m);
        }
        __syncthreads();   // protect ybuf before next quad overwrites it
    }
}

// ---------------------------------------------------------------------------
// Stage 2: per-unit FC1(140->100)+BN2+ReLU, FC2(100->1)+BN3+ReLU -> z (U,B)
// Block: 256 threads = 4 waves; lane = batch (64 per block), wave = 25-f slice.
// All weight/BN indices are wave-uniform -> s_load; inner loop is
// 1 ds_read_b128 + 20 v_fma(s,v,v). Pooled tile in LDS, row stride 148
// dwords (148%32=20 -> per-lane b128 reads tile all 32 banks).
// ---------------------------------------------------------------------------
__global__ __launch_bounds__(256, 4)
void fc_k(const float* __restrict__ pooled,   // (B,U,P)
          const float* __restrict__ w_fc1,    // (U,FC,P)
          const float* __restrict__ b_fc1,    // (U,FC)
          const float* __restrict__ g2,
          const float* __restrict__ be2,
          const float* __restrict__ m2,
          const float* __restrict__ v2,
          const float* __restrict__ w_fc2,    // (U,FC)
          const float* __restrict__ b_fc2,
          const float* __restrict__ g3,
          const float* __restrict__ be3,
          const float* __restrict__ m3,
          const float* __restrict__ v3,
          float* __restrict__ zbuf)           // (U, B) coalesced writes
{
    __shared__ float ps[64][148];             // 64 batches x 140 (stride 148)
    __shared__ float zred[3][64];
    const int tid = threadIdx.x;
    const int u   = blockIdx.y;
    const int bt  = blockIdx.x;

    const float4* pooled4 = (const float4*)pooled;
    for (int i = tid; i < 64 * 35; i += 256) {
        const int bl = i / 35, j = i - bl * 35;
        *(float4*)&ps[bl][4 * j] =
            pooled4[(((size_t)bt * 64 + bl) * U_ + u) * 35 + j];
    }
    __syncthreads();

    const int wv   = __builtin_amdgcn_readfirstlane(tid >> 6); // wave id 0..3
    const int lane = tid & 63;                                  // batch lane
    const float4* __restrict__ prow = (const float4*)&ps[lane][0];
    const int f00 = u * FC_ + 25 * wv;

    float zp = 0.f;
    for (int ch = 0; ch < 5; ++ch) {
        const int f0 = f00 + ch * 5;                       // global f row base
        const float* __restrict__ wb = w_fc1 + (size_t)f0 * P_;
        float acc[5] = {0.f, 0.f, 0.f, 0.f, 0.f};
#pragma unroll 5
        for (int jq = 0; jq < 35; ++jq) {
            const float4 pv = prow[jq];
#pragma unroll
            for (int f = 0; f < 5; ++f) {
                const float4 wv4 = *(const float4*)(wb + f * P_ + 4 * jq);
                acc[f] = fmaf(pv.x, wv4.x, acc[f]);
                acc[f] = fmaf(pv.y, wv4.y, acc[f]);
                acc[f] = fmaf(pv.z, wv4.z, acc[f]);
                acc[f] = fmaf(pv.w, wv4.w, acc[f]);
            }
        }
#pragma unroll
        for (int f = 0; f < 5; ++f) {
            const int fg = f0 + f;
            const float s2 = g2[fg] / sqrtf(v2[fg] + EPS_);
            const float o2 = (b_fc1[fg] - m2[fg]) * s2 + be2[fg];
            const float h = fmaxf(fmaf(acc[f], s2, o2), 0.f);
            zp = fmaf(h, w_fc2[fg], zp);
        }
    }

    if (wv) zred[wv - 1][lane] = zp;
    __syncthreads();
    if (wv == 0) {
        const float zsum = zp + zred[0][lane] + zred[1][lane] + zred[2][lane];
        const float s3 = g3[u] / sqrtf(v3[u] + EPS_);
        const float o3 = (b_fc2[u] - m3[u]) * s3 + be3[u];
        const float z = fmaxf(fmaf(zsum, s3, o3), 0.f);
        zbuf[(size_t)u * B_ + bt * 64 + lane] = z;   // coalesced
    }
}

// ---------------------------------------------------------------------------
// Stage 3: out[b] = sigmoid( sum_u z[u,b] * w_out[u] + b_out )
// zbuf is tiny (300 KB) and L2-resident after fc_k.
// ---------------------------------------------------------------------------
__global__ __launch_bounds__(320, 2)
void out_k(const float* __restrict__ zbuf,    // (U, B)
           const float* __restrict__ w_out,   // (U,1)
           const float* __restrict__ b_out,   // (1,)
           float* __restrict__ out)           // (B,1)
{
    __shared__ float red[5];
    const int tid = threadIdx.x;
    const int b   = blockIdx.x;

    float v = 0.f;
    if (tid < U_) v = zbuf[(size_t)tid * B_ + b] * w_out[tid];
#pragma unroll
    for (int o = 32; o > 0; o >>= 1) v += __shfl_xor(v, o);
    if ((tid & 63) == 0) red[tid >> 6] = v;
    __syncthreads();
    if (tid == 0) {
        const float s = red[0] + red[1] + red[2] + red[3] + red[4] + b_out[0];
        out[b] = 1.0f / (1.0f + __expf(-s));
    }
}

// ---------------------------------------------------------------------------
extern "C" void kernel_launch(void* const* d_in, const int* in_sizes, int n_in,
                              void* d_out, int out_size, void* d_ws, size_t ws_size,
                              hipStream_t stream)
{
    const float* input_seq = (const float*)d_in[0];   // (B,L,4)
    const float* w_conv    = (const float*)d_in[1];
    const float* b_conv    = (const float*)d_in[2];
    const float* g1        = (const float*)d_in[3];
    const float* be1       = (const float*)d_in[4];
    const float* m1        = (const float*)d_in[5];
    const float* v1        = (const float*)d_in[6];
    const float* w_fc1     = (const float*)d_in[7];
    const float* b_fc1     = (const float*)d_in[8];
    const float* g2        = (const float*)d_in[9];
    const float* be2       = (const float*)d_in[10];
    const float* m2        = (const float*)d_in[11];
    const float* v2        = (const float*)d_in[12];
    const float* w_fc2     = (const float*)d_in[13];
    const float* b_fc2     = (const float*)d_in[14];
    const float* g3        = (const float*)d_in[15];
    const float* be3       = (const float*)d_in[16];
    const float* m3        = (const float*)d_in[17];
    const float* v3        = (const float*)d_in[18];
    const float* w_out     = (const float*)d_in[19];
    const float* b_out     = (const float*)d_in[20];

    float* pooled = (float*)d_ws;                                   // B*U*P f32 = 43.0 MB
    float* zbuf   = (float*)((char*)d_ws + (size_t)B_ * U_ * P_ * sizeof(float)); // U*B f32

    conv_pool_k<<<dim3(U_ / UB_, B_), 256, 0, stream>>>(
        (const float4*)input_seq, w_conv, b_conv, g1, be1, m1, v1, pooled);

    fc_k<<<dim3(B_ / 64, U_), 256, 0, stream>>>(
        pooled, w_fc1, b_fc1, g2, be2, m2, v2, w_fc2, b_fc2, g3, be3, m3, v3, zbuf);

    out_k<<<dim3(B_), 320, 0, stream>>>(zbuf, w_out, b_out, (float*)d_out);
}

// Round 5
// 201.584 us; speedup vs baseline: 3.7355x; 3.7355x over previous
//
#include <hip/hip_runtime.h>
#include <hip/hip_bf16.h>
#include <math.h>

// Problem constants
#define U_   300
#define K_   19
#define FC_  100
#define B_   256
#define L_   1000
#define P_   140     // pooled length: windows l = 7p .. 7p+6, p < 140
#define EPS_ 1e-5f

typedef unsigned short ushort_t;
typedef __attribute__((ext_vector_type(8)))  short short8v;   // 8 bf16 = 4 VGPR
typedef __attribute__((ext_vector_type(16))) float f32x16;    // MFMA 32x32 acc

// f32 -> bf16 round-to-nearest-even (bit trick)
__device__ __forceinline__ ushort_t f2bf(float f) {
    union { float f; unsigned u; } a; a.f = f;
    unsigned r = a.u + 0x7fffu + ((a.u >> 16) & 1u);
    return (ushort_t)(r >> 16);
}

// ---------------------------------------------------------------------------
// pack_k: fold BN1 scale into conv weights, cast to bf16, pad (U,K4)=(320,80).
// GEMM patch ordering is j = 4*t + d (position-major, d fastest, matching
// x_flat = (L,D) memory order); w_conv is (u, d, t) with t fastest:
//   w_bf[u*80 + 4*t + d] = bf16( w_conv[u*76 + 19*d + t] * s1[u] )
// zero for u>=300 or j>=76.  o1g[u] = (b_conv-m1)*s1 + be1 (padded to 320).
// ---------------------------------------------------------------------------
__global__ __launch_bounds__(256, 4)
void pack_k(const float* __restrict__ w_conv, const float* __restrict__ b_conv,
            const float* __restrict__ g1, const float* __restrict__ be1,
            const float* __restrict__ m1, const float* __restrict__ v1,
            ushort_t* __restrict__ w_bf, float* __restrict__ o1g)
{
    const int t = blockIdx.x * 256 + threadIdx.x;
    if (t < 320 * 80) {
        const int u = t / 80, j = t - u * 80;
        float val = 0.f;
        if (u < U_ && j < 76) {
            const int tp = j >> 2;          // kernel position 0..18
            const int d  = j & 3;           // DNA channel 0..3
            const float s1 = g1[u] / sqrtf(v1[u] + EPS_);
            val = w_conv[u * 76 + 19 * d + tp] * s1;
        }
        w_bf[t] = f2bf(val);
    }
    if (t < 320) {
        float o = 0.f;
        if (t < U_) {
            const float s1 = g1[t] / sqrtf(v1[t] + EPS_);
            o = (b_conv[t] - m1[t]) * s1 + be1[t];
        }
        o1g[t] = o;
    }
}

// ---------------------------------------------------------------------------
// conv_mfma_k: implicit-GEMM conv + BN1 + maxpool(7,7) + exp -> pooled (B,U,P)
// Patch GEMM: C[l,u] = sum_j x_flat[4l+j] * w'[u][j], K=80 (B zero-padded).
// Block = (batch b, 35 pool windows = 245 l-rows -> 8 m-tiles of 32).
// 4 waves x 2 m-tiles; n-loop over 10 u-tiles of 32; 5 K-chunks of 16.
// A-frags from LDS-staged bf16 x (patch rows ARE contiguous x memory);
// B-frags per-lane from L2-resident packed w_bf.
// Frag layout (32x32x16): lane holds 8 contiguous k, lane-halves split K;
// C layout (m74/m101): col=lane&31, row=(reg&3)+8*(reg>>2)+4*(lane>>5).
// ---------------------------------------------------------------------------
__global__ __launch_bounds__(256, 4)
void conv_mfma_k(const float4* __restrict__ x4,        // (B,1000) float4 (D=4)
                 const ushort_t* __restrict__ w_bf,    // (320,80) bf16, s1-folded
                 const float* __restrict__ o1g,        // (320)
                 float* __restrict__ pooled)           // (B,U,P) f32
{
    __shared__ ushort_t xls[1104];       // bf16 x_flat[4*ls .. 4*ls+1103]
    __shared__ float ybuf[256][32];      // conv+BN rows x u-tile
    const int tid = threadIdx.x;
    const int b   = blockIdx.y;
    const int p0  = blockIdx.x * 35;     // first pool window
    const int ls  = p0 * 7;              // first l row

    // stage x rows ls..ls+275 as bf16 (guard past L)
    for (int i = tid; i < 276; i += 256) {
        const int gi = ls + i;
        float4 v = make_float4(0.f, 0.f, 0.f, 0.f);
        if (gi < L_) v = x4[(size_t)b * L_ + gi];
        ushort4 pk;
        pk.x = f2bf(v.x); pk.y = f2bf(v.y); pk.z = f2bf(v.z); pk.w = f2bf(v.w);
        *(ushort4*)&xls[4 * i] = pk;
    }
    __syncthreads();

    const int lane = tid & 63;
    const int wv   = tid >> 6;           // wave 0..3 -> m-tiles 2wv, 2wv+1
    const int half = lane >> 5;
    const int r32  = lane & 31;

    // A byte bases: element 4*row + kc*16 + half*8, 2B each
    const char* xbA = (const char*)xls + 8 * (64 * wv + r32) + 16 * half;
    const char* xbB = xbA + 256;         // +32 rows
    // B byte base: element u*80 + kc*16 + half*8
    const char* wbase = (const char*)w_bf + 16 * half + 160 * r32;

    for (int nt = 0; nt < 10; ++nt) {
        const int ug  = nt * 32 + r32;
        const float o1u = o1g[ug];

        short8v bfr[5];
        const char* wb = wbase + nt * 32 * 160;
#pragma unroll
        for (int kc = 0; kc < 5; ++kc)
            bfr[kc] = *(const short8v*)(wb + 32 * kc);

        f32x16 accA = {};
        f32x16 accB = {};
#pragma unroll
        for (int kc = 0; kc < 5; ++kc) {
            const short8v a0 = *(const short8v*)(xbA + 32 * kc);
            const short8v a1 = *(const short8v*)(xbB + 32 * kc);
            accA = __builtin_amdgcn_mfma_f32_32x32x16_bf16(a0, bfr[kc], accA, 0, 0, 0);
            accB = __builtin_amdgcn_mfma_f32_32x32x16_bf16(a1, bfr[kc], accB, 0, 0, 0);
        }

        // epilogue: + o1, scatter to ybuf (banks = col -> 2-way, free)
#pragma unroll
        for (int rg = 0; rg < 16; ++rg) {
            const int row = (rg & 3) + 8 * (rg >> 2) + 4 * half;
            ybuf[64 * wv + row][r32]      = accA[rg] + o1u;
            ybuf[64 * wv + 32 + row][r32] = accB[rg] + o1u;
        }
        __syncthreads();

        // pool 35 windows x 32 u; exp(max) == max then exp (monotone)
        for (int pp = tid; pp < 35 * 32; pp += 256) {
            const int ul = pp & 31, p = pp >> 5;
            const int ugo = nt * 32 + ul;
            if (ugo < U_) {
                const int r0 = 7 * p;
                float m = ybuf[r0][ul];
#pragma unroll
                for (int t = 1; t < 7; ++t) m = fmaxf(m, ybuf[r0 + t][ul]);
                pooled[((size_t)b * U_ + ugo) * P_ + p0 + p] = __expf(m);
            }
        }
        __syncthreads();   // ybuf reused next nt
    }
}

// ---------------------------------------------------------------------------
// Stage 2: per-unit FC1(140->100)+BN2+ReLU, FC2(100->1)+BN3+ReLU -> z (U,B)
// Block: 256 threads = 4 waves; lane = batch (64 per block), wave = 25-f slice.
// All weight/BN indices wave-uniform -> s_load; inner loop is
// 1 ds_read_b128 + 20 v_fma(s,v,v). ps row stride 148 (148%32=20, conflict-free).
// ---------------------------------------------------------------------------
__global__ __launch_bounds__(256, 4)
void fc_k(const float* __restrict__ pooled,   // (B,U,P)
          const float* __restrict__ w_fc1,    // (U,FC,P)
          const float* __restrict__ b_fc1,    // (U,FC)
          const float* __restrict__ g2,
          const float* __restrict__ be2,
          const float* __restrict__ m2,
          const float* __restrict__ v2,
          const float* __restrict__ w_fc2,    // (U,FC)
          const float* __restrict__ b_fc2,
          const float* __restrict__ g3,
          const float* __restrict__ be3,
          const float* __restrict__ m3,
          const float* __restrict__ v3,
          float* __restrict__ zbuf)           // (U, B)
{
    __shared__ float ps[64][148];
    __shared__ float zred[3][64];
    const int tid = threadIdx.x;
    const int u   = blockIdx.y;
    const int bt  = blockIdx.x;

    const float4* pooled4 = (const float4*)pooled;
    for (int i = tid; i < 64 * 35; i += 256) {
        const int bl = i / 35, j = i - bl * 35;
        *(float4*)&ps[bl][4 * j] =
            pooled4[(((size_t)bt * 64 + bl) * U_ + u) * 35 + j];
    }
    __syncthreads();

    const int wv   = __builtin_amdgcn_readfirstlane(tid >> 6);
    const int lane = tid & 63;
    const float4* __restrict__ prow = (const float4*)&ps[lane][0];
    const int f00 = u * FC_ + 25 * wv;

    float zp = 0.f;
    for (int ch = 0; ch < 5; ++ch) {
        const int f0 = f00 + ch * 5;
        const float* __restrict__ wb = w_fc1 + (size_t)f0 * P_;
        float acc[5] = {0.f, 0.f, 0.f, 0.f, 0.f};
#pragma unroll 5
        for (int jq = 0; jq < 35; ++jq) {
            const float4 pv = prow[jq];
#pragma unroll
            for (int f = 0; f < 5; ++f) {
                const float4 wv4 = *(const float4*)(wb + f * P_ + 4 * jq);
                acc[f] = fmaf(pv.x, wv4.x, acc[f]);
                acc[f] = fmaf(pv.y, wv4.y, acc[f]);
                acc[f] = fmaf(pv.z, wv4.z, acc[f]);
                acc[f] = fmaf(pv.w, wv4.w, acc[f]);
            }
        }
#pragma unroll
        for (int f = 0; f < 5; ++f) {
            const int fg = f0 + f;
            const float s2 = g2[fg] / sqrtf(v2[fg] + EPS_);
            const float o2 = (b_fc1[fg] - m2[fg]) * s2 + be2[fg];
            const float h = fmaxf(fmaf(acc[f], s2, o2), 0.f);
            zp = fmaf(h, w_fc2[fg], zp);
        }
    }

    if (wv) zred[wv - 1][lane] = zp;
    __syncthreads();
    if (wv == 0) {
        const float zsum = zp + zred[0][lane] + zred[1][lane] + zred[2][lane];
        const float s3 = g3[u] / sqrtf(v3[u] + EPS_);
        const float o3 = (b_fc2[u] - m3[u]) * s3 + be3[u];
        const float z = fmaxf(fmaf(zsum, s3, o3), 0.f);
        zbuf[(size_t)u * B_ + bt * 64 + lane] = z;
    }
}

// ---------------------------------------------------------------------------
// Stage 3: out[b] = sigmoid( sum_u z[u,b] * w_out[u] + b_out )
// ---------------------------------------------------------------------------
__global__ __launch_bounds__(320, 2)
void out_k(const float* __restrict__ zbuf,    // (U, B)
           const float* __restrict__ w_out,   // (U,1)
           const float* __restrict__ b_out,   // (1,)
           float* __restrict__ out)           // (B,1)
{
    __shared__ float red[5];
    const int tid = threadIdx.x;
    const int b   = blockIdx.x;

    float v = 0.f;
    if (tid < U_) v = zbuf[(size_t)tid * B_ + b] * w_out[tid];
#pragma unroll
    for (int o = 32; o > 0; o >>= 1) v += __shfl_xor(v, o);
    if ((tid & 63) == 0) red[tid >> 6] = v;
    __syncthreads();
    if (tid == 0) {
        const float s = red[0] + red[1] + red[2] + red[3] + red[4] + b_out[0];
        out[b] = 1.0f / (1.0f + __expf(-s));
    }
}

// ---------------------------------------------------------------------------
extern "C" void kernel_launch(void* const* d_in, const int* in_sizes, int n_in,
                              void* d_out, int out_size, void* d_ws, size_t ws_size,
                              hipStream_t stream)
{
    const float* input_seq = (const float*)d_in[0];   // (B,L,4)
    const float* w_conv    = (const float*)d_in[1];
    const float* b_conv    = (const float*)d_in[2];
    const float* g1        = (const float*)d_in[3];
    const float* be1       = (const float*)d_in[4];
    const float* m1        = (const float*)d_in[5];
    const float* v1        = (const float*)d_in[6];
    const float* w_fc1     = (const float*)d_in[7];
    const float* b_fc1     = (const float*)d_in[8];
    const float* g2        = (const float*)d_in[9];
    const float* be2       = (const float*)d_in[10];
    const float* m2        = (const float*)d_in[11];
    const float* v2        = (const float*)d_in[12];
    const float* w_fc2     = (const float*)d_in[13];
    const float* b_fc2     = (const float*)d_in[14];
    const float* g3        = (const float*)d_in[15];
    const float* be3       = (const float*)d_in[16];
    const float* m3        = (const float*)d_in[17];
    const float* v3        = (const float*)d_in[18];
    const float* w_out     = (const float*)d_in[19];
    const float* b_out     = (const float*)d_in[20];

    // Workspace layout (total 43,315,200 B):
    //   pooled: B*U*P f32 = 43,008,000
    //   zbuf:   U*B  f32  =    307,200  -- ALSO aliased (earlier in stream) by
    //           w_bf (320*80*2 = 51,200 B) + o1g (320*4 = 1,280 B): pack_k
    //           writes them, conv_mfma_k reads them, fc_k overwrites zbuf after.
    float*    pooled = (float*)d_ws;
    char*     ztail  = (char*)d_ws + (size_t)B_ * U_ * P_ * sizeof(float);
    float*    zbuf   = (float*)ztail;
    ushort_t* w_bf   = (ushort_t*)ztail;
    float*    o1g    = (float*)(ztail + 320 * 80 * sizeof(ushort_t));

    pack_k<<<dim3(100), 256, 0, stream>>>(w_conv, b_conv, g1, be1, m1, v1, w_bf, o1g);

    conv_mfma_k<<<dim3(4, B_), 256, 0, stream>>>(
        (const float4*)input_seq, w_bf, o1g, pooled);

    fc_k<<<dim3(B_ / 64, U_), 256, 0, stream>>>(
        pooled, w_fc1, b_fc1, g2, be2, m2, v2, w_fc2, b_fc2, g3, be3, m3, v3, zbuf);

    out_k<<<dim3(B_), 320, 0, stream>>>(zbuf, w_out, b_out, (float*)d_out);
}

// Round 6
// 113.837 us; speedup vs baseline: 6.6148x; 1.7708x over previous
//
#include <hip/hip_runtime.h>
#include <hip/hip_bf16.h>
#include <math.h>

// Problem constants
#define U_   300
#define K_   19
#define FC_  100
#define B_   256
#define L_   1000
#define P_   140     // pooled length
#define EPS_ 1e-5f
#define UP_  128     // FC padded to 4 n-tiles of 32
#define KP_  144     // P padded to 9 K-chunks of 16

typedef unsigned short ushort_t;
typedef __attribute__((ext_vector_type(8)))  short short8v;   // 8 bf16 = 4 VGPR
typedef __attribute__((ext_vector_type(16))) float f32x16;    // MFMA 32x32 acc

// f32 -> bf16 round-to-nearest-even (bit trick)
__device__ __forceinline__ ushort_t f2bf(float f) {
    union { float f; unsigned u; } a; a.f = f;
    unsigned r = a.u + 0x7fffu + ((a.u >> 16) & 1u);
    return (ushort_t)(r >> 16);
}

// ---------------------------------------------------------------------------
// pack_k: conv weights -> bf16 (U,80) with BN1 scale folded, GEMM ordering
// j = 4*t + d (d fastest, matching x (L,D) memory order).
// ---------------------------------------------------------------------------
__global__ __launch_bounds__(256, 4)
void pack_k(const float* __restrict__ w_conv, const float* __restrict__ b_conv,
            const float* __restrict__ g1, const float* __restrict__ be1,
            const float* __restrict__ m1, const float* __restrict__ v1,
            ushort_t* __restrict__ w_bf, float* __restrict__ o1g)
{
    const int t = blockIdx.x * 256 + threadIdx.x;
    if (t < 320 * 80) {
        const int u = t / 80, j = t - u * 80;
        float val = 0.f;
        if (u < U_ && j < 76) {
            const int tp = j >> 2;          // kernel position 0..18
            const int d  = j & 3;           // DNA channel 0..3
            const float s1 = g1[u] / sqrtf(v1[u] + EPS_);
            val = w_conv[u * 76 + 19 * d + tp] * s1;
        }
        w_bf[t] = f2bf(val);
    }
    if (t < 320) {
        float o = 0.f;
        if (t < U_) {
            const float s1 = g1[t] / sqrtf(v1[t] + EPS_);
            o = (b_conv[t] - m1[t]) * s1 + be1[t];
        }
        o1g[t] = o;
    }
}

// ---------------------------------------------------------------------------
// pack2_k: FC1 weights -> bf16 (U, UP=128, KP=144), BN2 scale folded, zero
// padded; o2p/w2p (U,128) f32 zero-padded (padded f contributes relu(0)*0=0).
// ---------------------------------------------------------------------------
__global__ __launch_bounds__(256, 4)
void pack2_k(const float* __restrict__ w_fc1, const float* __restrict__ b_fc1,
             const float* __restrict__ g2, const float* __restrict__ be2,
             const float* __restrict__ m2, const float* __restrict__ v2,
             const float* __restrict__ w_fc2,
             ushort_t* __restrict__ w1p, float* __restrict__ o2p,
             float* __restrict__ w2p)
{
    const int t = blockIdx.x * 256 + threadIdx.x;
    if (t < U_ * UP_ * KP_) {
        const int u = t / (UP_ * KP_);
        const int r = t - u * (UP_ * KP_);
        const int f = r / KP_;
        const int k = r - f * KP_;
        float val = 0.f;
        if (f < FC_ && k < P_) {
            const int fg = u * FC_ + f;
            const float s2 = g2[fg] / sqrtf(v2[fg] + EPS_);
            val = w_fc1[(size_t)fg * P_ + k] * s2;
        }
        w1p[t] = f2bf(val);
    }
    if (t < U_ * UP_) {
        const int u = t / UP_, f = t - u * UP_;
        float o2 = 0.f, w2 = 0.f;
        if (f < FC_) {
            const int fg = u * FC_ + f;
            const float s2 = g2[fg] / sqrtf(v2[fg] + EPS_);
            o2 = (b_fc1[fg] - m2[fg]) * s2 + be2[fg];
            w2 = w_fc2[fg];
        }
        o2p[t] = o2;
        w2p[t] = w2;
    }
}

// ---------------------------------------------------------------------------
// conv_mfma_k: implicit-GEMM conv + BN1 + maxpool(7,7) + exp -> pooled bf16
// C[l,u] = sum_j x_flat[4l+j]*w'[u][j], K=80. Block = (batch, 35 windows).
// 4 waves x 2 m-tiles; 10 n-tiles of 32 u; 5 K-chunks of 16.
// C layout: col=lane&31, row=(reg&3)+8*(reg>>2)+4*(lane>>5)  [m74/m101].
// ---------------------------------------------------------------------------
__global__ __launch_bounds__(256, 4)
void conv_mfma_k(const float4* __restrict__ x4,        // (B,1000) float4 (D=4)
                 const ushort_t* __restrict__ w_bf,    // (320,80) bf16
                 const float* __restrict__ o1g,        // (320)
                 ushort_t* __restrict__ pooled)        // (B,U,P) bf16
{
    __shared__ ushort_t xls[1104];       // bf16 x_flat[4*ls .. 4*ls+1103]
    __shared__ float ybuf[256][33];      // conv rows x u-tile (padded: both
                                         // epilogue and pool reads conflict-free)
    const int tid = threadIdx.x;
    const int b   = blockIdx.y;
    const int p0  = blockIdx.x * 35;     // first pool window
    const int ls  = p0 * 7;              // first l row

    for (int i = tid; i < 276; i += 256) {
        const int gi = ls + i;
        float4 v = make_float4(0.f, 0.f, 0.f, 0.f);
        if (gi < L_) v = x4[(size_t)b * L_ + gi];
        ushort4 pk;
        pk.x = f2bf(v.x); pk.y = f2bf(v.y); pk.z = f2bf(v.z); pk.w = f2bf(v.w);
        *(ushort4*)&xls[4 * i] = pk;
    }
    __syncthreads();

    const int lane = tid & 63;
    const int wv   = tid >> 6;           // wave -> m-tiles 2wv, 2wv+1
    const int half = lane >> 5;
    const int r32  = lane & 31;

    const char* xbA = (const char*)xls + 8 * (64 * wv + r32) + 16 * half;
    const char* xbB = xbA + 256;         // +32 rows
    const char* wbase = (const char*)w_bf + 16 * half + 160 * r32;

    for (int nt = 0; nt < 10; ++nt) {
        const float o1u = o1g[nt * 32 + r32];

        short8v bfr[5];
        const char* wb = wbase + nt * 32 * 160;
#pragma unroll
        for (int kc = 0; kc < 5; ++kc)
            bfr[kc] = *(const short8v*)(wb + 32 * kc);

        f32x16 accA = {};
        f32x16 accB = {};
#pragma unroll
        for (int kc = 0; kc < 5; ++kc) {
            const short8v a0 = *(const short8v*)(xbA + 32 * kc);
            const short8v a1 = *(const short8v*)(xbB + 32 * kc);
            accA = __builtin_amdgcn_mfma_f32_32x32x16_bf16(a0, bfr[kc], accA, 0, 0, 0);
            accB = __builtin_amdgcn_mfma_f32_32x32x16_bf16(a1, bfr[kc], accB, 0, 0, 0);
        }

#pragma unroll
        for (int rg = 0; rg < 16; ++rg) {
            const int row = (rg & 3) + 8 * (rg >> 2) + 4 * half;
            ybuf[64 * wv + row][r32]      = accA[rg] + o1u;
            ybuf[64 * wv + 32 + row][r32] = accB[rg] + o1u;
        }
        __syncthreads();

        // pool: p fastest across lanes -> 70B store segments per u
        for (int pp = tid; pp < 35 * 32; pp += 256) {
            const int ul = pp / 35;
            const int p  = pp - ul * 35;
            const int ugo = nt * 32 + ul;
            if (ugo < U_) {
                const int r0 = 7 * p;
                float m = ybuf[r0][ul];
#pragma unroll
                for (int t = 1; t < 7; ++t) m = fmaxf(m, ybuf[r0 + t][ul]);
                pooled[((size_t)b * U_ + ugo) * P_ + p0 + p] = f2bf(__expf(m));
            }
        }
        __syncthreads();   // ybuf reused next nt
    }
}

// ---------------------------------------------------------------------------
// fc_mfma_k: per-unit FC1 via MFMA + BN2+ReLU+FC2+BN3+ReLU -> z (U,B)
// Grid (4 bt, 300 u); block 4 waves = 2 m-tiles(32 batch) x 2 n-pairs(64 f).
// A: pooled bf16 rows (batch); B: packed w1p rows (f). 9 K-chunks.
// ---------------------------------------------------------------------------
__global__ __launch_bounds__(256, 4)
void fc_mfma_k(const ushort_t* __restrict__ pooled,  // (B,U,P) bf16
               const ushort_t* __restrict__ w1p,     // (U,128,144) bf16
               const float* __restrict__ o2p,        // (U,128)
               const float* __restrict__ w2p,        // (U,128)
               const float* __restrict__ b_fc2,
               const float* __restrict__ g3,
               const float* __restrict__ be3,
               const float* __restrict__ m3,
               const float* __restrict__ v3,
               float* __restrict__ zbuf)             // (U,B)
{
    __shared__ float zred[2][64][33];
    const int tid  = threadIdx.x;
    const int u    = blockIdx.y;
    const int bt   = blockIdx.x;          // 0..3 -> batches bt*64..+63
    const int lane = tid & 63;
    const int wv   = tid >> 6;
    const int half = lane >> 5;
    const int r32  = lane & 31;
    const int mi   = wv & 1;              // m-tile within block
    const int nh   = wv >> 1;             // n-pair: f tiles 2nh, 2nh+1

    const int brow = bt * 64 + mi * 32 + r32;
    const ushort_t* __restrict__ abase =
        pooled + ((size_t)brow * U_ + u) * P_ + half * 8;
    const ushort_t* __restrict__ bbase0 =
        w1p + ((size_t)u * UP_ + nh * 64 + r32) * KP_ + half * 8;
    const ushort_t* __restrict__ bbase1 = bbase0 + 32 * KP_;

    f32x16 acc0 = {};
    f32x16 acc1 = {};
#pragma unroll
    for (int kc = 0; kc < 9; ++kc) {
        const short8v a  = *(const short8v*)(abase  + kc * 16);
        const short8v b0 = *(const short8v*)(bbase0 + kc * 16);
        const short8v b1 = *(const short8v*)(bbase1 + kc * 16);
        acc0 = __builtin_amdgcn_mfma_f32_32x32x16_bf16(a, b0, acc0, 0, 0, 0);
        acc1 = __builtin_amdgcn_mfma_f32_32x32x16_bf16(a, b1, acc1, 0, 0, 0);
    }

    // BN2 + ReLU + FC2 partials (padded f: o2=w2=0 -> contributes 0)
    const int f0 = nh * 64 + r32;
    const float o20 = o2p[u * UP_ + f0],      w20 = w2p[u * UP_ + f0];
    const float o21 = o2p[u * UP_ + f0 + 32], w21 = w2p[u * UP_ + f0 + 32];
#pragma unroll
    for (int rg = 0; rg < 16; ++rg) {
        const float h0 = fmaxf(acc0[rg] + o20, 0.f);
        const float h1 = fmaxf(acc1[rg] + o21, 0.f);
        const int row  = (rg & 3) + 8 * (rg >> 2) + 4 * half;
        zred[nh][mi * 32 + row][r32] = fmaf(h0, w20, h1 * w21);
    }
    __syncthreads();

    if (tid < 64) {
        float s = 0.f;
#pragma unroll
        for (int j = 0; j < 32; ++j)
            s += zred[0][tid][j] + zred[1][tid][j];
        const float s3 = g3[u] / sqrtf(v3[u] + EPS_);
        const float o3 = (b_fc2[u] - m3[u]) * s3 + be3[u];
        zbuf[(size_t)u * B_ + bt * 64 + tid] = fmaxf(fmaf(s, s3, o3), 0.f);
    }
}

// ---------------------------------------------------------------------------
// out_k: out[b] = sigmoid( sum_u z[u,b] * w_out[u] + b_out )
// ---------------------------------------------------------------------------
__global__ __launch_bounds__(320, 2)
void out_k(const float* __restrict__ zbuf,    // (U, B)
           const float* __restrict__ w_out,   // (U,1)
           const float* __restrict__ b_out,   // (1,)
           float* __restrict__ out)           // (B,1)
{
    __shared__ float red[5];
    const int tid = threadIdx.x;
    const int b   = blockIdx.x;

    float v = 0.f;
    if (tid < U_) v = zbuf[(size_t)tid * B_ + b] * w_out[tid];
#pragma unroll
    for (int o = 32; o > 0; o >>= 1) v += __shfl_xor(v, o);
    if ((tid & 63) == 0) red[tid >> 6] = v;
    __syncthreads();
    if (tid == 0) {
        const float s = red[0] + red[1] + red[2] + red[3] + red[4] + b_out[0];
        out[b] = 1.0f / (1.0f + __expf(-s));
    }
}

// ---------------------------------------------------------------------------
extern "C" void kernel_launch(void* const* d_in, const int* in_sizes, int n_in,
                              void* d_out, int out_size, void* d_ws, size_t ws_size,
                              hipStream_t stream)
{
    const float* input_seq = (const float*)d_in[0];   // (B,L,4)
    const float* w_conv    = (const float*)d_in[1];
    const float* b_conv    = (const float*)d_in[2];
    const float* g1        = (const float*)d_in[3];
    const float* be1       = (const float*)d_in[4];
    const float* m1        = (const float*)d_in[5];
    const float* v1        = (const float*)d_in[6];
    const float* w_fc1     = (const float*)d_in[7];
    const float* b_fc1     = (const float*)d_in[8];
    const float* g2        = (const float*)d_in[9];
    const float* be2       = (const float*)d_in[10];
    const float* m2        = (const float*)d_in[11];
    const float* v2        = (const float*)d_in[12];
    const float* w_fc2     = (const float*)d_in[13];
    const float* b_fc2     = (const float*)d_in[14];
    const float* g3        = (const float*)d_in[15];
    const float* be3       = (const float*)d_in[16];
    const float* m3        = (const float*)d_in[17];
    const float* v3        = (const float*)d_in[18];
    const float* w_out     = (const float*)d_in[19];
    const float* b_out     = (const float*)d_in[20];

    // Workspace layout (33.2 MB of ws):
    char* p = (char*)d_ws;
    ushort_t* pooled = (ushort_t*)p;                 p += (size_t)B_ * U_ * P_ * 2;   // 21,504,000
    ushort_t* w1p    = (ushort_t*)p;                 p += (size_t)U_ * UP_ * KP_ * 2; // 11,059,200
    float*    o2p    = (float*)p;                    p += (size_t)U_ * UP_ * 4;       //    153,600
    float*    w2p    = (float*)p;                    p += (size_t)U_ * UP_ * 4;       //    153,600
    ushort_t* w_bf   = (ushort_t*)p;                 p += 320 * 80 * 2;               //     51,200
    float*    o1g    = (float*)p;                    p += 320 * 4;                    //      1,280
    float*    zbuf   = (float*)p;                    p += (size_t)U_ * B_ * 4;        //    307,200

    pack_k<<<dim3(100), 256, 0, stream>>>(w_conv, b_conv, g1, be1, m1, v1, w_bf, o1g);

    pack2_k<<<dim3((U_ * UP_ * KP_ + 255) / 256), 256, 0, stream>>>(
        w_fc1, b_fc1, g2, be2, m2, v2, w_fc2, w1p, o2p, w2p);

    conv_mfma_k<<<dim3(4, B_), 256, 0, stream>>>(
        (const float4*)input_seq, w_bf, o1g, pooled);

    fc_mfma_k<<<dim3(4, U_), 256, 0, stream>>>(
        pooled, w1p, o2p, w2p, b_fc2, g3, be3, m3, v3, zbuf);

    out_k<<<dim3(B_), 320, 0, stream>>>(zbuf, w_out, b_out, (float*)d_out);
}

// Round 7
// 76.045 us; speedup vs baseline: 9.9022x; 1.4970x over previous
//
#include <hip/hip_runtime.h>
#include <hip/hip_bf16.h>
#include <math.h>

// Problem constants
#define U_   300
#define K_   19
#define FC_  100
#define B_   256
#define L_   1000
#define P_   140     // pooled length
#define EPS_ 1e-5f
#define UP_  128     // FC padded to 4 n-tiles of 32
#define KP_  144     // P padded to 9 K-chunks of 16

typedef unsigned short ushort_t;
typedef __attribute__((ext_vector_type(8)))  short short8v;   // 8 bf16 = 4 VGPR
typedef __attribute__((ext_vector_type(16))) float f32x16;    // MFMA 32x32 acc

// f32 -> bf16 round-to-nearest-even (bit trick)
__device__ __forceinline__ ushort_t f2bf(float f) {
    union { float f; unsigned u; } a; a.f = f;
    unsigned r = a.u + 0x7fffu + ((a.u >> 16) & 1u);
    return (ushort_t)(r >> 16);
}

// ---------------------------------------------------------------------------
// pack_k: conv weights -> bf16 (U,80) with BN1 scale folded, GEMM ordering
// j = 4*t + d (d fastest, matching x (L,D) memory order).
// ---------------------------------------------------------------------------
__global__ __launch_bounds__(256, 4)
void pack_k(const float* __restrict__ w_conv, const float* __restrict__ b_conv,
            const float* __restrict__ g1, const float* __restrict__ be1,
            const float* __restrict__ m1, const float* __restrict__ v1,
            ushort_t* __restrict__ w_bf, float* __restrict__ o1g)
{
    const int t = blockIdx.x * 256 + threadIdx.x;
    if (t < 320 * 80) {
        const int u = t / 80, j = t - u * 80;
        float val = 0.f;
        if (u < U_ && j < 76) {
            const int tp = j >> 2;          // kernel position 0..18
            const int d  = j & 3;           // DNA channel 0..3
            const float s1 = g1[u] / sqrtf(v1[u] + EPS_);
            val = w_conv[u * 76 + 19 * d + tp] * s1;
        }
        w_bf[t] = f2bf(val);
    }
    if (t < 320) {
        float o = 0.f;
        if (t < U_) {
            const float s1 = g1[t] / sqrtf(v1[t] + EPS_);
            o = (b_conv[t] - m1[t]) * s1 + be1[t];
        }
        o1g[t] = o;
    }
}

// ---------------------------------------------------------------------------
// pack2_k: FC1 weights -> bf16 (U, UP=128, KP=144), BN2 scale folded, zero
// padded; o2p/w2p (U,128) f32 zero-padded (padded f contributes relu(0)*0=0).
// ---------------------------------------------------------------------------
__global__ __launch_bounds__(256, 4)
void pack2_k(const float* __restrict__ w_fc1, const float* __restrict__ b_fc1,
             const float* __restrict__ g2, const float* __restrict__ be2,
             const float* __restrict__ m2, const float* __restrict__ v2,
             const float* __restrict__ w_fc2,
             ushort_t* __restrict__ w1p, float* __restrict__ o2p,
             float* __restrict__ w2p)
{
    const int t = blockIdx.x * 256 + threadIdx.x;
    if (t < U_ * UP_ * KP_) {
        const int u = t / (UP_ * KP_);
        const int r = t - u * (UP_ * KP_);
        const int f = r / KP_;
        const int k = r - f * KP_;
        float val = 0.f;
        if (f < FC_ && k < P_) {
            const int fg = u * FC_ + f;
            const float s2 = g2[fg] / sqrtf(v2[fg] + EPS_);
            val = w_fc1[(size_t)fg * P_ + k] * s2;
        }
        w1p[t] = f2bf(val);
    }
    if (t < U_ * UP_) {
        const int u = t / UP_, f = t - u * UP_;
        float o2 = 0.f, w2 = 0.f;
        if (f < FC_) {
            const int fg = u * FC_ + f;
            const float s2 = g2[fg] / sqrtf(v2[fg] + EPS_);
            o2 = (b_fc1[fg] - m2[fg]) * s2 + be2[fg];
            w2 = w_fc2[fg];
        }
        o2p[t] = o2;
        w2p[t] = w2;
    }
}

// ---------------------------------------------------------------------------
// conv_mfma_k: implicit-GEMM conv + BN1 + maxpool + exp, pooling IN REGISTERS.
// Rows of each 32-row m-tile are PERMUTED so that each lane-half's C slots
// ({0-3,8-11,16-19,24-27}+4*half) hold two complete 7-row pool windows:
//   C row slot s: reg=(s&3)+4*(s>>3), h=(s>>2)&1
//   l-offset perm: reg<7 -> reg+7h | reg<14 -> reg+7+7h | else 28+(reg-14)+2h
// So window maxes = fmax over acc regs 0-6 and 7-13 (regs 14,15 spare).
// Windows of tile t: p = 4t + 2*which + half; cross-half shfl pairs them and
// each half stores one aligned ushort4 (4 windows x bf16).
// Block = (batch, 32 windows = 8 tiles); 4 waves x 2 tiles; 10 u-tiles.
// One barrier total; no ybuf.
// ---------------------------------------------------------------------------
__global__ __launch_bounds__(256, 4)
void conv_mfma_k(const float4* __restrict__ x4,        // (B,1000) float4 (D=4)
                 const ushort_t* __restrict__ w_bf,    // (320,80) bf16
                 const float* __restrict__ o1g,        // (320)
                 ushort_t* __restrict__ pooled)        // (B,U,P) bf16
{
    __shared__ ushort_t xls[1000];       // bf16 x_flat rows l0..l0+247
    const int tid = threadIdx.x;
    const int b   = blockIdx.y;
    const int bx  = blockIdx.x;          // 0..4
    const int w0  = bx * 32;             // first window of block
    const int l0  = w0 * 7;              // first conv row

    if (tid < 248) {
        const int gi = l0 + tid;
        float4 v = make_float4(0.f, 0.f, 0.f, 0.f);
        if (gi < L_) v = x4[(size_t)b * L_ + gi];
        ushort4 pk;
        pk.x = f2bf(v.x); pk.y = f2bf(v.y); pk.z = f2bf(v.z); pk.w = f2bf(v.w);
        *(ushort4*)&xls[4 * tid] = pk;
    }
    __syncthreads();

    const int lane = tid & 63;
    const int wv   = tid >> 6;           // wave -> tiles 2wv, 2wv+1
    const int half = lane >> 5;
    const int r32  = lane & 31;

    // permuted A-row offset for slot r32
    const int sreg = (r32 & 3) + 4 * (r32 >> 3);
    const int sh   = (r32 >> 2) & 1;
    const int off  = sreg < 7  ? sreg + 7 * sh
                   : sreg < 14 ? sreg + 7 + 7 * sh
                               : 28 + (sreg - 14) + 2 * sh;

    const char* xbA = (const char*)xls + 8 * (28 * (2 * wv)     + off) + 16 * half;
    const char* xbB = (const char*)xls + 8 * (28 * (2 * wv + 1) + off) + 16 * half;
    const char* wbase = (const char*)w_bf + 16 * half + 160 * r32;

    const int pA = w0 + 8 * wv;          // window base of tile A
    const int pB = pA + 4;               // window base of tile B

    for (int nt = 0; nt < 10; ++nt) {
        const int u = nt * 32 + r32;
        const float o1u = o1g[u];

        short8v bfr[5];
        const char* wb = wbase + nt * 5120;     // 32 rows * 160 B
#pragma unroll
        for (int kc = 0; kc < 5; ++kc)
            bfr[kc] = *(const short8v*)(wb + 32 * kc);

        f32x16 accA = {};
        f32x16 accB = {};
#pragma unroll
        for (int kc = 0; kc < 5; ++kc) {
            const short8v a0 = *(const short8v*)(xbA + 32 * kc);
            const short8v a1 = *(const short8v*)(xbB + 32 * kc);
            accA = __builtin_amdgcn_mfma_f32_32x32x16_bf16(a0, bfr[kc], accA, 0, 0, 0);
            accB = __builtin_amdgcn_mfma_f32_32x32x16_bf16(a1, bfr[kc], accB, 0, 0, 0);
        }

        // in-register pooling: window maxes over acc regs (o1 added after max)
        float mA0 = accA[0], mA1 = accA[7];
        float mB0 = accB[0], mB1 = accB[7];
#pragma unroll
        for (int j = 1; j < 7; ++j) { mA0 = fmaxf(mA0, accA[j]); mB0 = fmaxf(mB0, accB[j]); }
#pragma unroll
        for (int j = 8; j < 14; ++j) { mA1 = fmaxf(mA1, accA[j]); mB1 = fmaxf(mB1, accB[j]); }

        const unsigned pkA = (unsigned)f2bf(__expf(mA0 + o1u)) |
                             ((unsigned)f2bf(__expf(mA1 + o1u)) << 16);
        const unsigned pkB = (unsigned)f2bf(__expf(mB0 + o1u)) |
                             ((unsigned)f2bf(__expf(mB1 + o1u)) << 16);
        const unsigned oA = __shfl_xor(pkA, 32);
        const unsigned oB = __shfl_xor(pkB, 32);

        if (u < U_) {
            if (half == 0) {
                if (pA + 3 < P_) {     // own = p+0,p+2; other = p+1,p+3
                    ushort4 st;
                    st.x = (ushort_t)(pkA & 0xffff);
                    st.y = (ushort_t)(oA  & 0xffff);
                    st.z = (ushort_t)(pkA >> 16);
                    st.w = (ushort_t)(oA  >> 16);
                    *(ushort4*)&pooled[((size_t)b * U_ + u) * P_ + pA] = st;
                }
            } else {
                if (pB + 3 < P_) {     // own = p+1,p+3; other = p+0,p+2
                    ushort4 st;
                    st.x = (ushort_t)(oB  & 0xffff);
                    st.y = (ushort_t)(pkB & 0xffff);
                    st.z = (ushort_t)(oB  >> 16);
                    st.w = (ushort_t)(pkB >> 16);
                    *(ushort4*)&pooled[((size_t)b * U_ + u) * P_ + pB] = st;
                }
            }
        }
    }
}

// ---------------------------------------------------------------------------
// fc_mfma_k: per-unit FC1 via MFMA + BN2+ReLU+FC2+BN3+ReLU -> z (U,B)
// Grid (4 bt, 300 u); block 4 waves = 2 m-tiles(32 batch) x 2 n-pairs(64 f).
// ---------------------------------------------------------------------------
__global__ __launch_bounds__(256, 4)
void fc_mfma_k(const ushort_t* __restrict__ pooled,  // (B,U,P) bf16
               const ushort_t* __restrict__ w1p,     // (U,128,144) bf16
               const float* __restrict__ o2p,        // (U,128)
               const float* __restrict__ w2p,        // (U,128)
               const float* __restrict__ b_fc2,
               const float* __restrict__ g3,
               const float* __restrict__ be3,
               const float* __restrict__ m3,
               const float* __restrict__ v3,
               float* __restrict__ zbuf)             // (U,B)
{
    __shared__ float zred[2][64][33];
    const int tid  = threadIdx.x;
    const int u    = blockIdx.y;
    const int bt   = blockIdx.x;
    const int lane = tid & 63;
    const int wv   = tid >> 6;
    const int half = lane >> 5;
    const int r32  = lane & 31;
    const int mi   = wv & 1;
    const int nh   = wv >> 1;

    const int brow = bt * 64 + mi * 32 + r32;
    const ushort_t* __restrict__ abase =
        pooled + ((size_t)brow * U_ + u) * P_ + half * 8;
    const ushort_t* __restrict__ bbase0 =
        w1p + ((size_t)u * UP_ + nh * 64 + r32) * KP_ + half * 8;
    const ushort_t* __restrict__ bbase1 = bbase0 + 32 * KP_;

    f32x16 acc0 = {};
    f32x16 acc1 = {};
#pragma unroll
    for (int kc = 0; kc < 9; ++kc) {
        const short8v a  = *(const short8v*)(abase  + kc * 16);
        const short8v b0 = *(const short8v*)(bbase0 + kc * 16);
        const short8v b1 = *(const short8v*)(bbase1 + kc * 16);
        acc0 = __builtin_amdgcn_mfma_f32_32x32x16_bf16(a, b0, acc0, 0, 0, 0);
        acc1 = __builtin_amdgcn_mfma_f32_32x32x16_bf16(a, b1, acc1, 0, 0, 0);
    }

    const int f0 = nh * 64 + r32;
    const float o20 = o2p[u * UP_ + f0],      w20 = w2p[u * UP_ + f0];
    const float o21 = o2p[u * UP_ + f0 + 32], w21 = w2p[u * UP_ + f0 + 32];
#pragma unroll
    for (int rg = 0; rg < 16; ++rg) {
        const float h0 = fmaxf(acc0[rg] + o20, 0.f);
        const float h1 = fmaxf(acc1[rg] + o21, 0.f);
        const int row  = (rg & 3) + 8 * (rg >> 2) + 4 * half;
        zred[nh][mi * 32 + row][r32] = fmaf(h0, w20, h1 * w21);
    }
    __syncthreads();

    if (tid < 64) {
        float s = 0.f;
#pragma unroll
        for (int j = 0; j < 32; ++j)
            s += zred[0][tid][j] + zred[1][tid][j];
        const float s3 = g3[u] / sqrtf(v3[u] + EPS_);
        const float o3 = (b_fc2[u] - m3[u]) * s3 + be3[u];
        zbuf[(size_t)u * B_ + bt * 64 + tid] = fmaxf(fmaf(s, s3, o3), 0.f);
    }
}

// ---------------------------------------------------------------------------
// out_k: out[b] = sigmoid( sum_u z[u,b] * w_out[u] + b_out )
// ---------------------------------------------------------------------------
__global__ __launch_bounds__(320, 2)
void out_k(const float* __restrict__ zbuf,    // (U, B)
           const float* __restrict__ w_out,   // (U,1)
           const float* __restrict__ b_out,   // (1,)
           float* __restrict__ out)           // (B,1)
{
    __shared__ float red[5];
    const int tid = threadIdx.x;
    const int b   = blockIdx.x;

    float v = 0.f;
    if (tid < U_) v = zbuf[(size_t)tid * B_ + b] * w_out[tid];
#pragma unroll
    for (int o = 32; o > 0; o >>= 1) v += __shfl_xor(v, o);
    if ((tid & 63) == 0) red[tid >> 6] = v;
    __syncthreads();
    if (tid == 0) {
        const float s = red[0] + red[1] + red[2] + red[3] + red[4] + b_out[0];
        out[b] = 1.0f / (1.0f + __expf(-s));
    }
}

// ---------------------------------------------------------------------------
extern "C" void kernel_launch(void* const* d_in, const int* in_sizes, int n_in,
                              void* d_out, int out_size, void* d_ws, size_t ws_size,
                              hipStream_t stream)
{
    const float* input_seq = (const float*)d_in[0];   // (B,L,4)
    const float* w_conv    = (const float*)d_in[1];
    const float* b_conv    = (const float*)d_in[2];
    const float* g1        = (const float*)d_in[3];
    const float* be1       = (const float*)d_in[4];
    const float* m1        = (const float*)d_in[5];
    const float* v1        = (const float*)d_in[6];
    const float* w_fc1     = (const float*)d_in[7];
    const float* b_fc1     = (const float*)d_in[8];
    const float* g2        = (const float*)d_in[9];
    const float* be2       = (const float*)d_in[10];
    const float* m2        = (const float*)d_in[11];
    const float* v2        = (const float*)d_in[12];
    const float* w_fc2     = (const float*)d_in[13];
    const float* b_fc2     = (const float*)d_in[14];
    const float* g3        = (const float*)d_in[15];
    const float* be3       = (const float*)d_in[16];
    const float* m3        = (const float*)d_in[17];
    const float* v3        = (const float*)d_in[18];
    const float* w_out     = (const float*)d_in[19];
    const float* b_out     = (const float*)d_in[20];

    // Workspace layout (33.2 MB of ws):
    char* p = (char*)d_ws;
    ushort_t* pooled = (ushort_t*)p;                 p += (size_t)B_ * U_ * P_ * 2;   // 21,504,000
    ushort_t* w1p    = (ushort_t*)p;                 p += (size_t)U_ * UP_ * KP_ * 2; // 11,059,200
    float*    o2p    = (float*)p;                    p += (size_t)U_ * UP_ * 4;       //    153,600
    float*    w2p    = (float*)p;                    p += (size_t)U_ * UP_ * 4;       //    153,600
    ushort_t* w_bf   = (ushort_t*)p;                 p += 320 * 80 * 2;               //     51,200
    float*    o1g    = (float*)p;                    p += 320 * 4;                    //      1,280
    float*    zbuf   = (float*)p;                    p += (size_t)U_ * B_ * 4;        //    307,200

    pack_k<<<dim3(100), 256, 0, stream>>>(w_conv, b_conv, g1, be1, m1, v1, w_bf, o1g);

    pack2_k<<<dim3((U_ * UP_ * KP_ + 255) / 256), 256, 0, stream>>>(
        w_fc1, b_fc1, g2, be2, m2, v2, w_fc2, w1p, o2p, w2p);

    conv_mfma_k<<<dim3(5, B_), 256, 0, stream>>>(
        (const float4*)input_seq, w_bf, o1g, pooled);

    fc_mfma_k<<<dim3(4, U_), 256, 0, stream>>>(
        pooled, w1p, o2p, w2p, b_fc2, g3, be3, m3, v3, zbuf);

    out_k<<<dim3(B_), 320, 0, stream>>>(zbuf, w_out, b_out, (float*)d_out);
}

// Round 8
// 65.000 us; speedup vs baseline: 11.5847x; 1.1699x over previous
//
#include <hip/hip_runtime.h>
#include <hip/hip_bf16.h>
#include <math.h>

// Problem constants
#define U_   300
#define K_   19
#define FC_  100
#define B_   256
#define L_   1000
#define P_   140     // pooled length
#define EPS_ 1e-5f
#define UP_  128     // FC padded to 4 n-tiles of 32
#define KP_  144     // P padded to 9 K-chunks of 16

typedef unsigned short ushort_t;
typedef __attribute__((ext_vector_type(8)))  short short8v;   // 8 bf16 = 4 VGPR
typedef __attribute__((ext_vector_type(16))) float f32x16;    // MFMA 32x32 acc

// f32 -> bf16 round-to-nearest-even (bit trick)
__device__ __forceinline__ ushort_t f2bf(float f) {
    union { float f; unsigned u; } a; a.f = f;
    unsigned r = a.u + 0x7fffu + ((a.u >> 16) & 1u);
    return (ushort_t)(r >> 16);
}

// ---------------------------------------------------------------------------
// pack_all_k: all weight preprocessing in ONE dispatch.
//  (a) conv weights -> bf16 (320,80), BN1 scale folded, GEMM order j=4*t+d
//  (b) o1g[u] = (b_conv-m1)*s1+be1 (padded 320)
//  (c) FC1 weights -> bf16 (U,128,144), BN2 scale folded, zero padded
//  (d) o2p/w2p (U,128) f32 zero-padded
// ---------------------------------------------------------------------------
__global__ __launch_bounds__(256, 4)
void pack_all_k(const float* __restrict__ w_conv, const float* __restrict__ b_conv,
                const float* __restrict__ g1, const float* __restrict__ be1,
                const float* __restrict__ m1, const float* __restrict__ v1,
                const float* __restrict__ w_fc1, const float* __restrict__ b_fc1,
                const float* __restrict__ g2, const float* __restrict__ be2,
                const float* __restrict__ m2, const float* __restrict__ v2,
                const float* __restrict__ w_fc2,
                ushort_t* __restrict__ w_bf, float* __restrict__ o1g,
                ushort_t* __restrict__ w1p, float* __restrict__ o2p,
                float* __restrict__ w2p)
{
    const int t = blockIdx.x * 256 + threadIdx.x;
    if (t < U_ * UP_ * KP_) {
        const int u = t / (UP_ * KP_);
        const int r = t - u * (UP_ * KP_);
        const int f = r / KP_;
        const int k = r - f * KP_;
        float val = 0.f;
        if (f < FC_ && k < P_) {
            const int fg = u * FC_ + f;
            const float s2 = g2[fg] / sqrtf(v2[fg] + EPS_);
            val = w_fc1[(size_t)fg * P_ + k] * s2;
        }
        w1p[t] = f2bf(val);
    }
    if (t < U_ * UP_) {
        const int u = t / UP_, f = t - u * UP_;
        float o2 = 0.f, w2 = 0.f;
        if (f < FC_) {
            const int fg = u * FC_ + f;
            const float s2 = g2[fg] / sqrtf(v2[fg] + EPS_);
            o2 = (b_fc1[fg] - m2[fg]) * s2 + be2[fg];
            w2 = w_fc2[fg];
        }
        o2p[t] = o2;
        w2p[t] = w2;
    }
    if (t < 320 * 80) {
        const int u = t / 80, j = t - u * 80;
        float val = 0.f;
        if (u < U_ && j < 76) {
            const int tp = j >> 2;          // kernel position 0..18
            const int d  = j & 3;           // DNA channel 0..3
            const float s1 = g1[u] / sqrtf(v1[u] + EPS_);
            val = w_conv[u * 76 + 19 * d + tp] * s1;
        }
        w_bf[t] = f2bf(val);
    }
    if (t < 320) {
        float o = 0.f;
        if (t < U_) {
            const float s1 = g1[t] / sqrtf(v1[t] + EPS_);
            o = (b_conv[t] - m1[t]) * s1 + be1[t];
        }
        o1g[t] = o;
    }
}

// ---------------------------------------------------------------------------
// conv_mfma_k: implicit-GEMM conv + BN1 + maxpool + exp, pooling IN REGISTERS.
// Identical math to round 7; only the pooled layout changed to (U,B,P) so the
// fc stage reads fully-utilized cache lines.
// Rows of each 32-row m-tile are PERMUTED so each lane-half's C slots hold two
// complete 7-row pool windows; window max = fmax over acc regs; one barrier.
// ---------------------------------------------------------------------------
__global__ __launch_bounds__(256, 4)
void conv_mfma_k(const float4* __restrict__ x4,        // (B,1000) float4 (D=4)
                 const ushort_t* __restrict__ w_bf,    // (320,80) bf16
                 const float* __restrict__ o1g,        // (320)
                 ushort_t* __restrict__ pooled)        // (U,B,P) bf16
{
    __shared__ ushort_t xls[1000];       // bf16 x_flat rows l0..l0+247
    const int tid = threadIdx.x;
    const int b   = blockIdx.y;
    const int bx  = blockIdx.x;          // 0..4
    const int w0  = bx * 32;             // first window of block
    const int l0  = w0 * 7;              // first conv row

    if (tid < 248) {
        const int gi = l0 + tid;
        float4 v = make_float4(0.f, 0.f, 0.f, 0.f);
        if (gi < L_) v = x4[(size_t)b * L_ + gi];
        ushort4 pk;
        pk.x = f2bf(v.x); pk.y = f2bf(v.y); pk.z = f2bf(v.z); pk.w = f2bf(v.w);
        *(ushort4*)&xls[4 * tid] = pk;
    }
    __syncthreads();

    const int lane = tid & 63;
    const int wv   = tid >> 6;           // wave -> tiles 2wv, 2wv+1
    const int half = lane >> 5;
    const int r32  = lane & 31;

    // permuted A-row offset for slot r32
    const int sreg = (r32 & 3) + 4 * (r32 >> 3);
    const int sh   = (r32 >> 2) & 1;
    const int off  = sreg < 7  ? sreg + 7 * sh
                   : sreg < 14 ? sreg + 7 + 7 * sh
                               : 28 + (sreg - 14) + 2 * sh;

    const char* xbA = (const char*)xls + 8 * (28 * (2 * wv)     + off) + 16 * half;
    const char* xbB = (const char*)xls + 8 * (28 * (2 * wv + 1) + off) + 16 * half;
    const char* wbase = (const char*)w_bf + 16 * half + 160 * r32;

    const int pA = w0 + 8 * wv;          // window base of tile A
    const int pB = pA + 4;               // window base of tile B

    for (int nt = 0; nt < 10; ++nt) {
        const int u = nt * 32 + r32;
        const float o1u = o1g[u];

        short8v bfr[5];
        const char* wb = wbase + nt * 5120;     // 32 rows * 160 B
#pragma unroll
        for (int kc = 0; kc < 5; ++kc)
            bfr[kc] = *(const short8v*)(wb + 32 * kc);

        f32x16 accA = {};
        f32x16 accB = {};
#pragma unroll
        for (int kc = 0; kc < 5; ++kc) {
            const short8v a0 = *(const short8v*)(xbA + 32 * kc);
            const short8v a1 = *(const short8v*)(xbB + 32 * kc);
            accA = __builtin_amdgcn_mfma_f32_32x32x16_bf16(a0, bfr[kc], accA, 0, 0, 0);
            accB = __builtin_amdgcn_mfma_f32_32x32x16_bf16(a1, bfr[kc], accB, 0, 0, 0);
        }

        // in-register pooling: window maxes over acc regs (o1 added after max)
        float mA0 = accA[0], mA1 = accA[7];
        float mB0 = accB[0], mB1 = accB[7];
#pragma unroll
        for (int j = 1; j < 7; ++j) { mA0 = fmaxf(mA0, accA[j]); mB0 = fmaxf(mB0, accB[j]); }
#pragma unroll
        for (int j = 8; j < 14; ++j) { mA1 = fmaxf(mA1, accA[j]); mB1 = fmaxf(mB1, accB[j]); }

        const unsigned pkA = (unsigned)f2bf(__expf(mA0 + o1u)) |
                             ((unsigned)f2bf(__expf(mA1 + o1u)) << 16);
        const unsigned pkB = (unsigned)f2bf(__expf(mB0 + o1u)) |
                             ((unsigned)f2bf(__expf(mB1 + o1u)) << 16);
        const unsigned oA = __shfl_xor(pkA, 32);
        const unsigned oB = __shfl_xor(pkB, 32);

        if (u < U_) {
            if (half == 0) {
                if (pA + 3 < P_) {     // own = p+0,p+2; other = p+1,p+3
                    ushort4 st;
                    st.x = (ushort_t)(pkA & 0xffff);
                    st.y = (ushort_t)(oA  & 0xffff);
                    st.z = (ushort_t)(pkA >> 16);
                    st.w = (ushort_t)(oA  >> 16);
                    *(ushort4*)&pooled[((size_t)u * B_ + b) * P_ + pA] = st;
                }
            } else {
                if (pB + 3 < P_) {     // own = p+1,p+3; other = p+0,p+2
                    ushort4 st;
                    st.x = (ushort_t)(oB  & 0xffff);
                    st.y = (ushort_t)(pkB & 0xffff);
                    st.z = (ushort_t)(oB  >> 16);
                    st.w = (ushort_t)(pkB >> 16);
                    *(ushort4*)&pooled[((size_t)u * B_ + b) * P_ + pB] = st;
                }
            }
        }
    }
}

// ---------------------------------------------------------------------------
// fc_mfma_k: per-unit FC1 via MFMA + BN2+ReLU+FC2+BN3+ReLU -> z (U,B)
// Grid (2 bt, 300 u); block 4 waves; wave = 1 m-tile (32 batches) x ALL 4
// n-tiles (acc0..3, statically named). w1p slice read once per block;
// pooled (U,B,P) panel read with 100% line utilization.
// Padded f: w1p rows zero -> acc 0, o2=w2=0 -> contributes 0.
// Padded K (140..143): A garbage x B zero = 0.
// ---------------------------------------------------------------------------
__global__ __launch_bounds__(256, 3)
void fc_mfma_k(const ushort_t* __restrict__ pooled,  // (U,B,P) bf16
               const ushort_t* __restrict__ w1p,     // (U,128,144) bf16
               const float* __restrict__ o2p,        // (U,128)
               const float* __restrict__ w2p,        // (U,128)
               const float* __restrict__ b_fc2,
               const float* __restrict__ g3,
               const float* __restrict__ be3,
               const float* __restrict__ m3,
               const float* __restrict__ v3,
               float* __restrict__ zbuf)             // (U,B)
{
    __shared__ float zred[128][33];
    const int tid  = threadIdx.x;
    const int u    = blockIdx.y;
    const int bt   = blockIdx.x;          // 0/1 -> batches bt*128..+127
    const int lane = tid & 63;
    const int wv   = tid >> 6;            // m-tile within the 128-batch panel
    const int half = lane >> 5;
    const int r32  = lane & 31;

    const int brow = bt * 128 + wv * 32 + r32;
    const ushort_t* __restrict__ abase =
        pooled + ((size_t)u * B_ + brow) * P_ + half * 8;
    const ushort_t* __restrict__ bbase =
        w1p + ((size_t)u * UP_ + r32) * KP_ + half * 8;

    f32x16 acc0 = {}, acc1 = {}, acc2 = {}, acc3 = {};
#pragma unroll
    for (int kc = 0; kc < 9; ++kc) {
        const short8v a  = *(const short8v*)(abase + kc * 16);
        const short8v b0 = *(const short8v*)(bbase            + kc * 16);
        const short8v b1 = *(const short8v*)(bbase + 32 * KP_ + kc * 16);
        const short8v b2 = *(const short8v*)(bbase + 64 * KP_ + kc * 16);
        const short8v b3 = *(const short8v*)(bbase + 96 * KP_ + kc * 16);
        acc0 = __builtin_amdgcn_mfma_f32_32x32x16_bf16(a, b0, acc0, 0, 0, 0);
        acc1 = __builtin_amdgcn_mfma_f32_32x32x16_bf16(a, b1, acc1, 0, 0, 0);
        acc2 = __builtin_amdgcn_mfma_f32_32x32x16_bf16(a, b2, acc2, 0, 0, 0);
        acc3 = __builtin_amdgcn_mfma_f32_32x32x16_bf16(a, b3, acc3, 0, 0, 0);
    }

    // BN2 + ReLU + FC2 partial over the 4 f-cols this lane owns
    const int fb = u * UP_ + r32;
    const float o20 = o2p[fb],      w20 = w2p[fb];
    const float o21 = o2p[fb + 32], w21 = w2p[fb + 32];
    const float o22 = o2p[fb + 64], w22 = w2p[fb + 64];
    const float o23 = o2p[fb + 96], w23 = w2p[fb + 96];
#pragma unroll
    for (int rg = 0; rg < 16; ++rg) {
        const int row = (rg & 3) + 8 * (rg >> 2) + 4 * half;
        float s = fmaxf(acc0[rg] + o20, 0.f) * w20;
        s = fmaf(fmaxf(acc1[rg] + o21, 0.f), w21, s);
        s = fmaf(fmaxf(acc2[rg] + o22, 0.f), w22, s);
        s = fmaf(fmaxf(acc3[rg] + o23, 0.f), w23, s);
        zred[wv * 32 + row][r32] = s;
    }
    __syncthreads();

    // reduce 32 lane-partials per batch row; 128 rows
    if (tid < 128) {
        float s = 0.f;
#pragma unroll
        for (int j = 0; j < 32; ++j) s += zred[tid][j];
        const float s3 = g3[u] / sqrtf(v3[u] + EPS_);
        const float o3 = (b_fc2[u] - m3[u]) * s3 + be3[u];
        zbuf[(size_t)u * B_ + bt * 128 + tid] = fmaxf(fmaf(s, s3, o3), 0.f);
    }
}

// ---------------------------------------------------------------------------
// out_k: out[b] = sigmoid( sum_u z[u,b] * w_out[u] + b_out )
// ---------------------------------------------------------------------------
__global__ __launch_bounds__(320, 2)
void out_k(const float* __restrict__ zbuf,    // (U, B)
           const float* __restrict__ w_out,   // (U,1)
           const float* __restrict__ b_out,   // (1,)
           float* __restrict__ out)           // (B,1)
{
    __shared__ float red[5];
    const int tid = threadIdx.x;
    const int b   = blockIdx.x;

    float v = 0.f;
    if (tid < U_) v = zbuf[(size_t)tid * B_ + b] * w_out[tid];
#pragma unroll
    for (int o = 32; o > 0; o >>= 1) v += __shfl_xor(v, o);
    if ((tid & 63) == 0) red[tid >> 6] = v;
    __syncthreads();
    if (tid == 0) {
        const float s = red[0] + red[1] + red[2] + red[3] + red[4] + b_out[0];
        out[b] = 1.0f / (1.0f + __expf(-s));
    }
}

// ---------------------------------------------------------------------------
extern "C" void kernel_launch(void* const* d_in, const int* in_sizes, int n_in,
                              void* d_out, int out_size, void* d_ws, size_t ws_size,
                              hipStream_t stream)
{
    const float* input_seq = (const float*)d_in[0];   // (B,L,4)
    const float* w_conv    = (const float*)d_in[1];
    const float* b_conv    = (const float*)d_in[2];
    const float* g1        = (const float*)d_in[3];
    const float* be1       = (const float*)d_in[4];
    const float* m1        = (const float*)d_in[5];
    const float* v1        = (const float*)d_in[6];
    const float* w_fc1     = (const float*)d_in[7];
    const float* b_fc1     = (const float*)d_in[8];
    const float* g2        = (const float*)d_in[9];
    const float* be2       = (const float*)d_in[10];
    const float* m2        = (const float*)d_in[11];
    const float* v2        = (const float*)d_in[12];
    const float* w_fc2     = (const float*)d_in[13];
    const float* b_fc2     = (const float*)d_in[14];
    const float* g3        = (const float*)d_in[15];
    const float* be3       = (const float*)d_in[16];
    const float* m3        = (const float*)d_in[17];
    const float* v3        = (const float*)d_in[18];
    const float* w_out     = (const float*)d_in[19];
    const float* b_out     = (const float*)d_in[20];

    // Workspace layout (33.2 MB of ws):
    char* p = (char*)d_ws;
    ushort_t* pooled = (ushort_t*)p;                 p += (size_t)B_ * U_ * P_ * 2;   // 21,504,000
    ushort_t* w1p    = (ushort_t*)p;                 p += (size_t)U_ * UP_ * KP_ * 2; // 11,059,200
    float*    o2p    = (float*)p;                    p += (size_t)U_ * UP_ * 4;       //    153,600
    float*    w2p    = (float*)p;                    p += (size_t)U_ * UP_ * 4;       //    153,600
    ushort_t* w_bf   = (ushort_t*)p;                 p += 320 * 80 * 2;               //     51,200
    float*    o1g    = (float*)p;                    p += 320 * 4;                    //      1,280
    float*    zbuf   = (float*)p;                    p += (size_t)U_ * B_ * 4;        //    307,200

    pack_all_k<<<dim3((U_ * UP_ * KP_ + 255) / 256), 256, 0, stream>>>(
        w_conv, b_conv, g1, be1, m1, v1,
        w_fc1, b_fc1, g2, be2, m2, v2, w_fc2,
        w_bf, o1g, w1p, o2p, w2p);

    conv_mfma_k<<<dim3(5, B_), 256, 0, stream>>>(
        (const float4*)input_seq, w_bf, o1g, pooled);

    fc_mfma_k<<<dim3(2, U_), 256, 0, stream>>>(
        pooled, w1p, o2p, w2p, b_fc2, g3, be3, m3, v3, zbuf);

    out_k<<<dim3(B_), 320, 0, stream>>>(zbuf, w_out, b_out, (float*)d_out);
}

// Round 10
// 63.265 us; speedup vs baseline: 11.9025x; 1.0274x over previous
//
#include <hip/hip_runtime.h>
#include <hip/hip_bf16.h>
#include <math.h>

// Problem constants
#define U_   300
#define K_   19
#define FC_  100
#define B_   256
#define L_   1000
#define P_   140     // pooled length
#define EPS_ 1e-5f
#define UP_  128     // FC padded to 4 n-tiles of 32
#define KP_  144     // P padded to 9 K-chunks of 16

typedef unsigned short ushort_t;
typedef __attribute__((ext_vector_type(8)))  short short8v;   // 8 bf16 = 4 VGPR
typedef __attribute__((ext_vector_type(16))) float f32x16;    // MFMA 32x32 acc

// f32 -> bf16 round-to-nearest-even (bit trick)
__device__ __forceinline__ ushort_t f2bf(float f) {
    union { float f; unsigned u; } a; a.f = f;
    unsigned r = a.u + 0x7fffu + ((a.u >> 16) & 1u);
    return (ushort_t)(r >> 16);
}

// ---------------------------------------------------------------------------
// pack_all_k: all weight preprocessing in ONE dispatch.
//  (a) conv weights -> bf16 (320,80), BN1 scale folded, GEMM order j=4*t+d
//  (b) o1g[u] = (b_conv-m1)*s1+be1 (padded 320)
//  (c) FC1 weights -> bf16 (U,128,144), BN2 scale folded, zero padded
//  (d) o2p/w2p (U,128) f32 zero-padded
// ---------------------------------------------------------------------------
__global__ __launch_bounds__(256, 4)
void pack_all_k(const float* __restrict__ w_conv, const float* __restrict__ b_conv,
                const float* __restrict__ g1, const float* __restrict__ be1,
                const float* __restrict__ m1, const float* __restrict__ v1,
                const float* __restrict__ w_fc1, const float* __restrict__ b_fc1,
                const float* __restrict__ g2, const float* __restrict__ be2,
                const float* __restrict__ m2, const float* __restrict__ v2,
                const float* __restrict__ w_fc2,
                ushort_t* __restrict__ w_bf, float* __restrict__ o1g,
                ushort_t* __restrict__ w1p, float* __restrict__ o2p,
                float* __restrict__ w2p)
{
    const int t = blockIdx.x * 256 + threadIdx.x;
    if (t < U_ * UP_ * KP_) {
        const int u = t / (UP_ * KP_);
        const int r = t - u * (UP_ * KP_);
        const int f = r / KP_;
        const int k = r - f * KP_;
        float val = 0.f;
        if (f < FC_ && k < P_) {
            const int fg = u * FC_ + f;
            const float s2 = g2[fg] / sqrtf(v2[fg] + EPS_);
            val = w_fc1[(size_t)fg * P_ + k] * s2;
        }
        w1p[t] = f2bf(val);
    }
    if (t < U_ * UP_) {
        const int u = t / UP_, f = t - u * UP_;
        float o2 = 0.f, w2 = 0.f;
        if (f < FC_) {
            const int fg = u * FC_ + f;
            const float s2 = g2[fg] / sqrtf(v2[fg] + EPS_);
            o2 = (b_fc1[fg] - m2[fg]) * s2 + be2[fg];
            w2 = w_fc2[fg];
        }
        o2p[t] = o2;
        w2p[t] = w2;
    }
    if (t < 320 * 80) {
        const int u = t / 80, j = t - u * 80;
        float val = 0.f;
        if (u < U_ && j < 76) {
            const int tp = j >> 2;          // kernel position 0..18
            const int d  = j & 3;           // DNA channel 0..3
            const float s1 = g1[u] / sqrtf(v1[u] + EPS_);
            val = w_conv[u * 76 + 19 * d + tp] * s1;
        }
        w_bf[t] = f2bf(val);
    }
    if (t < 320) {
        float o = 0.f;
        if (t < U_) {
            const float s1 = g1[t] / sqrtf(v1[t] + EPS_);
            o = (b_conv[t] - m1[t]) * s1 + be1[t];
        }
        o1g[t] = o;
    }
}

// ---------------------------------------------------------------------------
// conv_mfma_k: implicit-GEMM conv + BN1 + maxpool + exp, pooling IN REGISTERS.
// Block covers 28 windows (5 blocks x 28 = 140 exact): 7 m-tiles; 4 waves x 2
// tiles, wave 3 has tile A only. A-fragments are nt-invariant -> hoisted into
// registers ONCE. B-fragments + o1 double-buffered (prefetch nt+1).
// STAGING: GEMM rows 0..199 (incl. spares) each read x4 rows l..l+18 ->
// must stage 199+19+1 = 220 rows (fragment reads reach element 875 < 880).
// Row permutation per 32-row tile puts two complete 7-row pool windows in
// each lane-half's C slots; window max = fmax over acc regs; one barrier.
// ---------------------------------------------------------------------------
__global__ __launch_bounds__(256, 2)
void conv_mfma_k(const float4* __restrict__ x4,        // (B,1000) float4 (D=4)
                 const ushort_t* __restrict__ w_bf,    // (320,80) bf16
                 const float* __restrict__ o1g,        // (320)
                 ushort_t* __restrict__ pooled)        // (U,B,P) bf16
{
    __shared__ ushort_t xls[880];        // bf16 x_flat rows l0..l0+219
    const int tid = threadIdx.x;
    const int b   = blockIdx.y;
    const int bx  = blockIdx.x;          // 0..4
    const int w0  = bx * 28;             // first window of block
    const int l0  = w0 * 7;              // first conv row (bx*196, max 784)

    if (tid < 220) {
        const int gi = l0 + tid;
        float4 v = make_float4(0.f, 0.f, 0.f, 0.f);
        if (gi < L_) v = x4[(size_t)b * L_ + gi];
        ushort4 pk;
        pk.x = f2bf(v.x); pk.y = f2bf(v.y); pk.z = f2bf(v.z); pk.w = f2bf(v.w);
        *(ushort4*)&xls[4 * tid] = pk;
    }
    __syncthreads();

    const int lane = tid & 63;
    const int wv   = tid >> 6;
    const int half = lane >> 5;
    const int r32  = lane & 31;
    const bool hasB = (wv < 3);          // wave-uniform
    const int tA = 2 * wv;               // tiles 0,2,4,6
    const int tB = hasB ? (2 * wv + 1) : 0;  // tiles 1,3,5 (clamped for wv3)

    // permuted A-row offset for slot r32
    const int sreg = (r32 & 3) + 4 * (r32 >> 3);
    const int sh   = (r32 >> 2) & 1;
    const int off  = sreg < 7  ? sreg + 7 * sh
                   : sreg < 14 ? sreg + 7 + 7 * sh
                               : 28 + (sreg - 14) + 2 * sh;

    const char* xbA = (const char*)xls + 8 * (28 * tA + off) + 16 * half;
    const char* xbB = (const char*)xls + 8 * (28 * tB + off) + 16 * half;
    const char* wbase = (const char*)w_bf + 16 * half + 160 * r32;

    // hoist nt-invariant A-fragments into registers
    short8v aA[5], aB[5];
#pragma unroll
    for (int kc = 0; kc < 5; ++kc) {
        aA[kc] = *(const short8v*)(xbA + 32 * kc);
        aB[kc] = *(const short8v*)(xbB + 32 * kc);
    }

    const int pA = w0 + 8 * wv;          // window base of tile A (<=136)
    const int pB = pA + 4;               // window base of tile B

    // B-frag + o1 double buffer
    short8v bfr[5];
#pragma unroll
    for (int kc = 0; kc < 5; ++kc)
        bfr[kc] = *(const short8v*)(wbase + 32 * kc);
    float o1u = o1g[r32];

    for (int nt = 0; nt < 10; ++nt) {
        const int ntn = (nt < 9) ? nt + 1 : nt;     // dummy reload on last iter
        short8v bnx[5];
        const char* wn = wbase + ntn * 5120;        // 32 rows * 160 B
#pragma unroll
        for (int kc = 0; kc < 5; ++kc)
            bnx[kc] = *(const short8v*)(wn + 32 * kc);
        const float o1n = o1g[ntn * 32 + r32];

        f32x16 accA = {};
#pragma unroll
        for (int kc = 0; kc < 5; ++kc)
            accA = __builtin_amdgcn_mfma_f32_32x32x16_bf16(aA[kc], bfr[kc], accA, 0, 0, 0);
        f32x16 accB = {};
        if (hasB) {
#pragma unroll
            for (int kc = 0; kc < 5; ++kc)
                accB = __builtin_amdgcn_mfma_f32_32x32x16_bf16(aB[kc], bfr[kc], accB, 0, 0, 0);
        }

        // in-register pooling (o1 added after max; exp monotone)
        float mA0 = accA[0], mA1 = accA[7];
#pragma unroll
        for (int j = 1; j < 7; ++j)  mA0 = fmaxf(mA0, accA[j]);
#pragma unroll
        for (int j = 8; j < 14; ++j) mA1 = fmaxf(mA1, accA[j]);
        const unsigned pkA = (unsigned)f2bf(__expf(mA0 + o1u)) |
                             ((unsigned)f2bf(__expf(mA1 + o1u)) << 16);
        const unsigned oA = __shfl_xor(pkA, 32);

        const int u = nt * 32 + r32;
        if (u < U_ && half == 0) {       // tile A store: windows pA..pA+3
            ushort4 st;
            st.x = (ushort_t)(pkA & 0xffff);
            st.y = (ushort_t)(oA  & 0xffff);
            st.z = (ushort_t)(pkA >> 16);
            st.w = (ushort_t)(oA  >> 16);
            *(ushort4*)&pooled[((size_t)u * B_ + b) * P_ + pA] = st;
        }

        if (hasB) {
            float mB0 = accB[0], mB1 = accB[7];
#pragma unroll
            for (int j = 1; j < 7; ++j)  mB0 = fmaxf(mB0, accB[j]);
#pragma unroll
            for (int j = 8; j < 14; ++j) mB1 = fmaxf(mB1, accB[j]);
            const unsigned pkB = (unsigned)f2bf(__expf(mB0 + o1u)) |
                                 ((unsigned)f2bf(__expf(mB1 + o1u)) << 16);
            const unsigned oB = __shfl_xor(pkB, 32);
            if (u < U_ && half == 1) {   // tile B store: windows pB..pB+3
                ushort4 st;
                st.x = (ushort_t)(oB  & 0xffff);
                st.y = (ushort_t)(pkB & 0xffff);
                st.z = (ushort_t)(oB  >> 16);
                st.w = (ushort_t)(pkB >> 16);
                *(ushort4*)&pooled[((size_t)u * B_ + b) * P_ + pB] = st;
            }
        }

#pragma unroll
        for (int kc = 0; kc < 5; ++kc) bfr[kc] = bnx[kc];
        o1u = o1n;
    }
}

// ---------------------------------------------------------------------------
// fc_mfma_k: per-unit FC1 via MFMA + BN2+ReLU+FC2+BN3+ReLU -> zT (B,304)
// Grid (2 bt, 300 u); block 4 waves; wave = 1 m-tile (32 batches) x ALL 4
// n-tiles. Software-pipelined K loop (kc+1 operands issued during kc MFMAs).
// zT written transposed so out_k reads coalesced rows.
// ---------------------------------------------------------------------------
__global__ __launch_bounds__(256, 3)
void fc_mfma_k(const ushort_t* __restrict__ pooled,  // (U,B,P) bf16
               const ushort_t* __restrict__ w1p,     // (U,128,144) bf16
               const float* __restrict__ o2p,        // (U,128)
               const float* __restrict__ w2p,        // (U,128)
               const float* __restrict__ b_fc2,
               const float* __restrict__ g3,
               const float* __restrict__ be3,
               const float* __restrict__ m3,
               const float* __restrict__ v3,
               float* __restrict__ zT)               // (B,304)
{
    __shared__ float zred[128][33];
    const int tid  = threadIdx.x;
    const int u    = blockIdx.y;
    const int bt   = blockIdx.x;          // 0/1 -> batches bt*128..+127
    const int lane = tid & 63;
    const int wv   = tid >> 6;            // m-tile within the 128-batch panel
    const int half = lane >> 5;
    const int r32  = lane & 31;

    const int brow = bt * 128 + wv * 32 + r32;
    const ushort_t* __restrict__ abase =
        pooled + ((size_t)u * B_ + brow) * P_ + half * 8;
    const ushort_t* __restrict__ bbase =
        w1p + ((size_t)u * UP_ + r32) * KP_ + half * 8;

    // software pipeline: current operands in regs, next issued during MFMA
    short8v ac  = *(const short8v*)(abase);
    short8v b0c = *(const short8v*)(bbase);
    short8v b1c = *(const short8v*)(bbase + 32 * KP_);
    short8v b2c = *(const short8v*)(bbase + 64 * KP_);
    short8v b3c = *(const short8v*)(bbase + 96 * KP_);

    f32x16 acc0 = {}, acc1 = {}, acc2 = {}, acc3 = {};
#pragma unroll
    for (int kc = 0; kc < 9; ++kc) {
        const int kn = (kc < 8) ? kc + 1 : kc;
        const short8v an  = *(const short8v*)(abase + kn * 16);
        const short8v b0n = *(const short8v*)(bbase            + kn * 16);
        const short8v b1n = *(const short8v*)(bbase + 32 * KP_ + kn * 16);
        const short8v b2n = *(const short8v*)(bbase + 64 * KP_ + kn * 16);
        const short8v b3n = *(const short8v*)(bbase + 96 * KP_ + kn * 16);
        acc0 = __builtin_amdgcn_mfma_f32_32x32x16_bf16(ac, b0c, acc0, 0, 0, 0);
        acc1 = __builtin_amdgcn_mfma_f32_32x32x16_bf16(ac, b1c, acc1, 0, 0, 0);
        acc2 = __builtin_amdgcn_mfma_f32_32x32x16_bf16(ac, b2c, acc2, 0, 0, 0);
        acc3 = __builtin_amdgcn_mfma_f32_32x32x16_bf16(ac, b3c, acc3, 0, 0, 0);
        ac = an; b0c = b0n; b1c = b1n; b2c = b2n; b3c = b3n;
    }

    // BN2 + ReLU + FC2 partial over the 4 f-cols this lane owns
    const int fb = u * UP_ + r32;
    const float o20 = o2p[fb],      w20 = w2p[fb];
    const float o21 = o2p[fb + 32], w21 = w2p[fb + 32];
    const float o22 = o2p[fb + 64], w22 = w2p[fb + 64];
    const float o23 = o2p[fb + 96], w23 = w2p[fb + 96];
#pragma unroll
    for (int rg = 0; rg < 16; ++rg) {
        const int row = (rg & 3) + 8 * (rg >> 2) + 4 * half;
        float s = fmaxf(acc0[rg] + o20, 0.f) * w20;
        s = fmaf(fmaxf(acc1[rg] + o21, 0.f), w21, s);
        s = fmaf(fmaxf(acc2[rg] + o22, 0.f), w22, s);
        s = fmaf(fmaxf(acc3[rg] + o23, 0.f), w23, s);
        zred[wv * 32 + row][r32] = s;
    }
    __syncthreads();

    // reduce 32 lane-partials per batch row; write transposed (B,304)
    if (tid < 128) {
        float s = 0.f;
#pragma unroll
        for (int j = 0; j < 32; ++j) s += zred[tid][j];
        const float s3 = g3[u] / sqrtf(v3[u] + EPS_);
        const float o3 = (b_fc2[u] - m3[u]) * s3 + be3[u];
        zT[(size_t)(bt * 128 + tid) * 304 + u] = fmaxf(fmaf(s, s3, o3), 0.f);
    }
}

// ---------------------------------------------------------------------------
// out_k: out[b] = sigmoid( dot(zT[b,0:300], w_out) + b_out ), coalesced f4.
// 300 = 75 float4 exactly.
// ---------------------------------------------------------------------------
__global__ __launch_bounds__(64, 8)
void out_k(const float* __restrict__ zT,      // (B,304)
           const float* __restrict__ w_out,   // (U,1)
           const float* __restrict__ b_out,   // (1,)
           float* __restrict__ out)           // (B,1)
{
    const int lane = threadIdx.x;
    const int b    = blockIdx.x;
    const float4* zr = (const float4*)(zT + (size_t)b * 304);
    const float4* w4 = (const float4*)w_out;

    float s = 0.f;
    for (int i = lane; i < 75; i += 64) {
        const float4 z = zr[i], w = w4[i];
        s += z.x * w.x + z.y * w.y + z.z * w.z + z.w * w.w;
    }
#pragma unroll
    for (int o = 32; o > 0; o >>= 1) s += __shfl_xor(s, o);
    if (lane == 0)
        out[b] = 1.0f / (1.0f + __expf(-(s + b_out[0])));
}

// ---------------------------------------------------------------------------
extern "C" void kernel_launch(void* const* d_in, const int* in_sizes, int n_in,
                              void* d_out, int out_size, void* d_ws, size_t ws_size,
                              hipStream_t stream)
{
    const float* input_seq = (const float*)d_in[0];   // (B,L,4)
    const float* w_conv    = (const float*)d_in[1];
    const float* b_conv    = (const float*)d_in[2];
    const float* g1        = (const float*)d_in[3];
    const float* be1       = (const float*)d_in[4];
    const float* m1        = (const float*)d_in[5];
    const float* v1        = (const float*)d_in[6];
    const float* w_fc1     = (const float*)d_in[7];
    const float* b_fc1     = (const float*)d_in[8];
    const float* g2        = (const float*)d_in[9];
    const float* be2       = (const float*)d_in[10];
    const float* m2        = (const float*)d_in[11];
    const float* v2        = (const float*)d_in[12];
    const float* w_fc2     = (const float*)d_in[13];
    const float* b_fc2     = (const float*)d_in[14];
    const float* g3        = (const float*)d_in[15];
    const float* be3       = (const float*)d_in[16];
    const float* m3        = (const float*)d_in[17];
    const float* v3        = (const float*)d_in[18];
    const float* w_out     = (const float*)d_in[19];
    const float* b_out     = (const float*)d_in[20];

    // Workspace layout (~33.2 MB of ws):
    char* p = (char*)d_ws;
    ushort_t* pooled = (ushort_t*)p;                 p += (size_t)B_ * U_ * P_ * 2;   // 21,504,000
    ushort_t* w1p    = (ushort_t*)p;                 p += (size_t)U_ * UP_ * KP_ * 2; // 11,059,200
    float*    o2p    = (float*)p;                    p += (size_t)U_ * UP_ * 4;       //    153,600
    float*    w2p    = (float*)p;                    p += (size_t)U_ * UP_ * 4;       //    153,600
    ushort_t* w_bf   = (ushort_t*)p;                 p += 320 * 80 * 2;               //     51,200
    float*    o1g    = (float*)p;                    p += 320 * 4;                    //      1,280
    float*    zT     = (float*)p;                    p += (size_t)B_ * 304 * 4;       //    311,296

    pack_all_k<<<dim3((U_ * UP_ * KP_ + 255) / 256), 256, 0, stream>>>(
        w_conv, b_conv, g1, be1, m1, v1,
        w_fc1, b_fc1, g2, be2, m2, v2, w_fc2,
        w_bf, o1g, w1p, o2p, w2p);

    conv_mfma_k<<<dim3(5, B_), 256, 0, stream>>>(
        (const float4*)input_seq, w_bf, o1g, pooled);

    fc_mfma_k<<<dim3(2, U_), 256, 0, stream>>>(
        pooled, w1p, o2p, w2p, b_fc2, g3, be3, m3, v3, zT);

    out_k<<<dim3(B_), 64, 0, stream>>>(zT, w_out, b_out, (float*)d_out);
}

// Round 11
// 62.183 us; speedup vs baseline: 12.1095x; 1.0174x over previous
//
#include <hip/hip_runtime.h>
#include <hip/hip_bf16.h>
#include <math.h>

// Problem constants
#define U_   300
#define K_   19
#define FC_  100
#define B_   256
#define L_   1000
#define P_   140     // pooled length
#define EPS_ 1e-5f
#define WLD_ 144     // fc LDS row stride (bf16): 288 B, 16-B aligned

typedef unsigned short ushort_t;
typedef __attribute__((ext_vector_type(8)))  short short8v;   // 8 bf16 = 4 VGPR
typedef __attribute__((ext_vector_type(16))) float f32x16;    // MFMA 32x32 acc

// f32 -> bf16 round-to-nearest-even (bit trick)
__device__ __forceinline__ ushort_t f2bf(float f) {
    union { float f; unsigned u; } a; a.f = f;
    unsigned r = a.u + 0x7fffu + ((a.u >> 16) & 1u);
    return (ushort_t)(r >> 16);
}

// ---------------------------------------------------------------------------
// pack_conv_k: conv weights -> bf16 (320,80), BN1 scale folded, GEMM order
// j = 4*t + d (d fastest, matching x (L,D) memory order); o1g padded to 320.
// ---------------------------------------------------------------------------
__global__ __launch_bounds__(256, 4)
void pack_conv_k(const float* __restrict__ w_conv, const float* __restrict__ b_conv,
                 const float* __restrict__ g1, const float* __restrict__ be1,
                 const float* __restrict__ m1, const float* __restrict__ v1,
                 ushort_t* __restrict__ w_bf, float* __restrict__ o1g)
{
    const int t = blockIdx.x * 256 + threadIdx.x;
    if (t < 320 * 80) {
        const int u = t / 80, j = t - u * 80;
        float val = 0.f;
        if (u < U_ && j < 76) {
            const int tp = j >> 2;          // kernel position 0..18
            const int d  = j & 3;           // DNA channel 0..3
            const float s1 = g1[u] / sqrtf(v1[u] + EPS_);
            val = w_conv[u * 76 + 19 * d + tp] * s1;
        }
        w_bf[t] = f2bf(val);
    }
    if (t < 320) {
        float o = 0.f;
        if (t < U_) {
            const float s1 = g1[t] / sqrtf(v1[t] + EPS_);
            o = (b_conv[t] - m1[t]) * s1 + be1[t];
        }
        o1g[t] = o;
    }
}

// ---------------------------------------------------------------------------
// conv_mfma_k: implicit-GEMM conv + BN1 + maxpool + exp, pooling IN REGISTERS.
// 448 threads = 7 waves; wave wv owns m-tile wv (4 windows, 28 rows + spares).
// Block covers 28 windows (5 blocks x 28 = 140 exact). A-fragments hoisted
// once; B-fragments + o1 double-buffered. Staging: rows 0..199 read x4 rows
// l..l+18 -> stage 220 rows (fragment reads reach element 875 < 880).
// Per-tile row permutation puts two complete 7-row pool windows in each
// lane-half's C slots; window max = fmax over acc regs; one barrier.
// ---------------------------------------------------------------------------
__global__ __launch_bounds__(448, 3)
void conv_mfma_k(const float4* __restrict__ x4,        // (B,1000) float4 (D=4)
                 const ushort_t* __restrict__ w_bf,    // (320,80) bf16
                 const float* __restrict__ o1g,        // (320)
                 ushort_t* __restrict__ pooled)        // (U,B,P) bf16
{
    __shared__ ushort_t xls[880];        // bf16 x_flat rows l0..l0+219
    const int tid = threadIdx.x;
    const int b   = blockIdx.y;
    const int bx  = blockIdx.x;          // 0..4
    const int w0  = bx * 28;             // first window of block
    const int l0  = w0 * 7;              // first conv row (bx*196, max 784)

    if (tid < 220) {
        const int gi = l0 + tid;
        float4 v = make_float4(0.f, 0.f, 0.f, 0.f);
        if (gi < L_) v = x4[(size_t)b * L_ + gi];
        ushort4 pk;
        pk.x = f2bf(v.x); pk.y = f2bf(v.y); pk.z = f2bf(v.z); pk.w = f2bf(v.w);
        *(ushort4*)&xls[4 * tid] = pk;
    }
    __syncthreads();

    const int lane = tid & 63;
    const int wv   = tid >> 6;           // 0..6 -> m-tile wv
    const int half = lane >> 5;
    const int r32  = lane & 31;

    // permuted A-row offset for slot r32
    const int sreg = (r32 & 3) + 4 * (r32 >> 3);
    const int sh   = (r32 >> 2) & 1;
    const int off  = sreg < 7  ? sreg + 7 * sh
                   : sreg < 14 ? sreg + 7 + 7 * sh
                               : 28 + (sreg - 14) + 2 * sh;

    const char* xb    = (const char*)xls + 8 * (28 * wv + off) + 16 * half;
    const char* wbase = (const char*)w_bf + 16 * half + 160 * r32;

    // hoist nt-invariant A-fragments into registers
    short8v aA[5];
#pragma unroll
    for (int kc = 0; kc < 5; ++kc)
        aA[kc] = *(const short8v*)(xb + 32 * kc);

    const int pA = w0 + 4 * wv;          // window base of this tile (<=136)

    // B-frag + o1 double buffer
    short8v bfr[5];
#pragma unroll
    for (int kc = 0; kc < 5; ++kc)
        bfr[kc] = *(const short8v*)(wbase + 32 * kc);
    float o1u = o1g[r32];

    for (int nt = 0; nt < 10; ++nt) {
        const int ntn = (nt < 9) ? nt + 1 : nt;     // dummy reload on last iter
        short8v bnx[5];
        const char* wn = wbase + ntn * 5120;        // 32 rows * 160 B
#pragma unroll
        for (int kc = 0; kc < 5; ++kc)
            bnx[kc] = *(const short8v*)(wn + 32 * kc);
        const float o1n = o1g[ntn * 32 + r32];

        f32x16 acc = {};
#pragma unroll
        for (int kc = 0; kc < 5; ++kc)
            acc = __builtin_amdgcn_mfma_f32_32x32x16_bf16(aA[kc], bfr[kc], acc, 0, 0, 0);

        // in-register pooling (o1 added after max; exp monotone)
        float m0 = acc[0], m1 = acc[7];
#pragma unroll
        for (int j = 1; j < 7; ++j)  m0 = fmaxf(m0, acc[j]);
#pragma unroll
        for (int j = 8; j < 14; ++j) m1 = fmaxf(m1, acc[j]);
        const unsigned pk = (unsigned)f2bf(__expf(m0 + o1u)) |
                            ((unsigned)f2bf(__expf(m1 + o1u)) << 16);
        const unsigned ot = __shfl_xor(pk, 32);

        const int u = nt * 32 + r32;
        if (u < U_ && half == 0) {       // windows pA..pA+3 (pA+3 <= 139 always)
            ushort4 st;
            st.x = (ushort_t)(pk & 0xffff);   // p+0 (own m0)
            st.y = (ushort_t)(ot & 0xffff);   // p+1 (other m0)
            st.z = (ushort_t)(pk >> 16);      // p+2 (own m1)
            st.w = (ushort_t)(ot >> 16);      // p+3 (other m1)
            *(ushort4*)&pooled[((size_t)u * B_ + b) * P_ + pA] = st;
        }

#pragma unroll
        for (int kc = 0; kc < 5; ++kc) bfr[kc] = bnx[kc];
        o1u = o1n;
    }
}

// ---------------------------------------------------------------------------
// fc_mfma_k: per-unit FC1 via MFMA + BN2+ReLU+FC2+BN3+ReLU -> zT (B,304)
// Grid (2 bt, 300 u); 4 waves = 4 m-tiles (32 batches each) x all 4 n-tiles.
// B-operand: raw w_fc1 f32 panel staged ONCE per block into LDS as bf16
// (UNSCALED); BN2 scale s2 applied in the f32 epilogue (same math).
// k 140..143 zeroed in LDS; f rows >=100 clamped to row 99, epilogue
// s2/o2/w2 = 0 kills their contribution.
// ---------------------------------------------------------------------------
__global__ __launch_bounds__(256, 3)
void fc_mfma_k(const ushort_t* __restrict__ pooled,  // (U,B,P) bf16
               const float* __restrict__ w_fc1,      // (U,FC,P) f32
               const float* __restrict__ b_fc1,
               const float* __restrict__ g2,
               const float* __restrict__ be2,
               const float* __restrict__ m2,
               const float* __restrict__ v2,
               const float* __restrict__ w_fc2,
               const float* __restrict__ b_fc2,
               const float* __restrict__ g3,
               const float* __restrict__ be3,
               const float* __restrict__ m3,
               const float* __restrict__ v3,
               float* __restrict__ zT)               // (B,304)
{
    __shared__ ushort_t wlds[FC_ * WLD_];  // 100 rows x 144 bf16 = 28.8 KB
    __shared__ float zred[128][33];
    const int tid  = threadIdx.x;
    const int u    = blockIdx.y;
    const int bt   = blockIdx.x;          // 0/1 -> batches bt*128..+127

    // stage raw w_fc1 panel -> bf16 LDS (coalesced float4 reads)
    const float* __restrict__ wsrc = w_fc1 + (size_t)u * FC_ * P_;
    for (int idx = tid; idx < FC_ * 35; idx += 256) {
        const int f = idx / 35, j = idx - f * 35;
        const float4 v = *(const float4*)(wsrc + f * P_ + 4 * j);
        ushort4 pk;
        pk.x = f2bf(v.x); pk.y = f2bf(v.y); pk.z = f2bf(v.z); pk.w = f2bf(v.w);
        *(ushort4*)&wlds[f * WLD_ + 4 * j] = pk;
    }
    for (int idx = tid; idx < FC_ * 4; idx += 256) {
        const int f = idx >> 2, k = 140 + (idx & 3);
        wlds[f * WLD_ + k] = 0;
    }
    __syncthreads();

    const int lane = tid & 63;
    const int wv   = tid >> 6;            // m-tile within the 128-batch panel
    const int half = lane >> 5;
    const int r32  = lane & 31;

    const int brow = bt * 128 + wv * 32 + r32;
    const ushort_t* __restrict__ abase =
        pooled + ((size_t)u * B_ + brow) * P_ + half * 8;

    const ushort_t* __restrict__ bl0 = &wlds[r32 * WLD_ + half * 8];
    const ushort_t* __restrict__ bl1 = &wlds[(32 + r32) * WLD_ + half * 8];
    const ushort_t* __restrict__ bl2 = &wlds[(64 + r32) * WLD_ + half * 8];
    const int f3c = (96 + r32 < FC_) ? (96 + r32) : (FC_ - 1);   // clamp
    const ushort_t* __restrict__ bl3 = &wlds[f3c * WLD_ + half * 8];

    // A software-pipelined; B from LDS (low latency)
    short8v ac = *(const short8v*)(abase);
    f32x16 acc0 = {}, acc1 = {}, acc2 = {}, acc3 = {};
#pragma unroll
    for (int kc = 0; kc < 9; ++kc) {
        const int kn = (kc < 8) ? kc + 1 : kc;
        const short8v an = *(const short8v*)(abase + kn * 16);
        const short8v b0 = *(const short8v*)(bl0 + kc * 16);
        const short8v b1 = *(const short8v*)(bl1 + kc * 16);
        const short8v b2 = *(const short8v*)(bl2 + kc * 16);
        const short8v b3 = *(const short8v*)(bl3 + kc * 16);
        acc0 = __builtin_amdgcn_mfma_f32_32x32x16_bf16(ac, b0, acc0, 0, 0, 0);
        acc1 = __builtin_amdgcn_mfma_f32_32x32x16_bf16(ac, b1, acc1, 0, 0, 0);
        acc2 = __builtin_amdgcn_mfma_f32_32x32x16_bf16(ac, b2, acc2, 0, 0, 0);
        acc3 = __builtin_amdgcn_mfma_f32_32x32x16_bf16(ac, b3, acc3, 0, 0, 0);
        ac = an;
    }

    // inline BN2 params per lane (4 f-columns)
    float s2[4], o2[4], w2[4];
#pragma unroll
    for (int n = 0; n < 4; ++n) {
        const int f = n * 32 + r32;
        if (f < FC_) {
            const int fg = u * FC_ + f;
            const float ss = g2[fg] / sqrtf(v2[fg] + EPS_);
            s2[n] = ss;
            o2[n] = (b_fc1[fg] - m2[fg]) * ss + be2[fg];
            w2[n] = w_fc2[fg];
        } else {
            s2[n] = 0.f; o2[n] = 0.f; w2[n] = 0.f;
        }
    }
#pragma unroll
    for (int rg = 0; rg < 16; ++rg) {
        const int row = (rg & 3) + 8 * (rg >> 2) + 4 * half;
        float s = fmaxf(fmaf(acc0[rg], s2[0], o2[0]), 0.f) * w2[0];
        s = fmaf(fmaxf(fmaf(acc1[rg], s2[1], o2[1]), 0.f), w2[1], s);
        s = fmaf(fmaxf(fmaf(acc2[rg], s2[2], o2[2]), 0.f), w2[2], s);
        s = fmaf(fmaxf(fmaf(acc3[rg], s2[3], o2[3]), 0.f), w2[3], s);
        zred[wv * 32 + row][r32] = s;
    }
    __syncthreads();

    // reduce 32 lane-partials per batch row; write transposed (B,304)
    if (tid < 128) {
        float s = 0.f;
#pragma unroll
        for (int j = 0; j < 32; ++j) s += zred[tid][j];
        const float s3 = g3[u] / sqrtf(v3[u] + EPS_);
        const float o3 = (b_fc2[u] - m3[u]) * s3 + be3[u];
        zT[(size_t)(bt * 128 + tid) * 304 + u] = fmaxf(fmaf(s, s3, o3), 0.f);
    }
}

// ---------------------------------------------------------------------------
// out_k: out[b] = sigmoid( dot(zT[b,0:300], w_out) + b_out ), coalesced f4.
// ---------------------------------------------------------------------------
__global__ __launch_bounds__(64, 8)
void out_k(const float* __restrict__ zT,      // (B,304)
           const float* __restrict__ w_out,   // (U,1)
           const float* __restrict__ b_out,   // (1,)
           float* __restrict__ out)           // (B,1)
{
    const int lane = threadIdx.x;
    const int b    = blockIdx.x;
    const float4* zr = (const float4*)(zT + (size_t)b * 304);
    const float4* w4 = (const float4*)w_out;

    float s = 0.f;
    for (int i = lane; i < 75; i += 64) {
        const float4 z = zr[i], w = w4[i];
        s += z.x * w.x + z.y * w.y + z.z * w.z + z.w * w.w;
    }
#pragma unroll
    for (int o = 32; o > 0; o >>= 1) s += __shfl_xor(s, o);
    if (lane == 0)
        out[b] = 1.0f / (1.0f + __expf(-(s + b_out[0])));
}

// ---------------------------------------------------------------------------
extern "C" void kernel_launch(void* const* d_in, const int* in_sizes, int n_in,
                              void* d_out, int out_size, void* d_ws, size_t ws_size,
                              hipStream_t stream)
{
    const float* input_seq = (const float*)d_in[0];   // (B,L,4)
    const float* w_conv    = (const float*)d_in[1];
    const float* b_conv    = (const float*)d_in[2];
    const float* g1        = (const float*)d_in[3];
    const float* be1       = (const float*)d_in[4];
    const float* m1        = (const float*)d_in[5];
    const float* v1        = (const float*)d_in[6];
    const float* w_fc1     = (const float*)d_in[7];
    const float* b_fc1     = (const float*)d_in[8];
    const float* g2        = (const float*)d_in[9];
    const float* be2       = (const float*)d_in[10];
    const float* m2        = (const float*)d_in[11];
    const float* v2        = (const float*)d_in[12];
    const float* w_fc2     = (const float*)d_in[13];
    const float* b_fc2     = (const float*)d_in[14];
    const float* g3        = (const float*)d_in[15];
    const float* be3       = (const float*)d_in[16];
    const float* m3        = (const float*)d_in[17];
    const float* v3        = (const float*)d_in[18];
    const float* w_out     = (const float*)d_in[19];
    const float* b_out     = (const float*)d_in[20];

    // Workspace layout (~21.9 MB of ws):
    char* p = (char*)d_ws;
    ushort_t* pooled = (ushort_t*)p;   p += (size_t)B_ * U_ * P_ * 2;   // 21,504,000
    ushort_t* w_bf   = (ushort_t*)p;   p += 320 * 80 * 2;               //     51,200
    float*    o1g    = (float*)p;      p += 320 * 4;                    //      1,280
    float*    zT     = (float*)p;      p += (size_t)B_ * 304 * 4;       //    311,296

    pack_conv_k<<<dim3(100), 256, 0, stream>>>(
        w_conv, b_conv, g1, be1, m1, v1, w_bf, o1g);

    conv_mfma_k<<<dim3(5, B_), 448, 0, stream>>>(
        (const float4*)input_seq, w_bf, o1g, pooled);

    fc_mfma_k<<<dim3(2, U_), 256, 0, stream>>>(
        pooled, w_fc1, b_fc1, g2, be2, m2, v2, w_fc2, b_fc2,
        g3, be3, m3, v3, zT);

    out_k<<<dim3(B_), 64, 0, stream>>>(zT, w_out, b_out, (float*)d_out);
}